// Round 7
// baseline (513.380 us; speedup 1.0000x reference)
//
#include <hip/hip_runtime.h>
#include <hip/hip_bf16.h>

typedef unsigned short u16;
typedef unsigned int u32;
typedef __attribute__((ext_vector_type(2))) float f32x2;
typedef __attribute__((ext_vector_type(4))) float f32x4;
typedef __attribute__((ext_vector_type(4))) u32 u32x4;
typedef __attribute__((ext_vector_type(8))) short s16x8;

#define AS1 __attribute__((address_space(1)))
#define AS3 __attribute__((address_space(3)))

#define NB 4
#define TTOK 1024
#define DD 1024
#define NH 16
#define HD 64
#define MT 4096      // B*T tokens
#define NCH 16       // chunks per (b,h)
#define CLEN 64      // chunk length

static __device__ __forceinline__ float b2f(u16 u) {
  union { unsigned int u; float f; } c; c.u = ((unsigned int)u) << 16; return c.f;
}
static __device__ __forceinline__ u16 f2b(float f) {
  union { float f; unsigned int u; } c; c.f = f;
  return (u16)((c.u + 0x7fffu + ((c.u >> 16) & 1u)) >> 16);
}
// direct global->LDS async copy, 16B per lane
static __device__ __forceinline__ void gload16(const u16* g, u16* l) {
  __builtin_amdgcn_global_load_lds((const AS1 u32*)g, (AS3 u32*)l, 16, 0, 0);
}
// LDS byte-offset swizzle (involution, keeps 16B chunks intact)
static __device__ __forceinline__ int swz(int lin) {
  return lin ^ (((lin >> 9) & 3) << 5) ^ (((lin >> 7) & 1) << 4);
}

// ---------------- weight conversion / packing ----------------
__global__ __launch_bounds__(256) void convW(const float* __restrict__ s0, const float* __restrict__ s1,
                                             const float* __restrict__ s2, const float* __restrict__ s3,
                                             const float* __restrict__ s4, u16* __restrict__ dst) {
  long f = ((long)blockIdx.x * 256 + threadIdx.x) << 2;   // 5 * 1048576 elems
  int sel = (int)(f >> 20);
  const float* s = sel == 0 ? s0 : sel == 1 ? s1 : sel == 2 ? s2 : sel == 3 ? s3 : s4;
  long off = f & 1048575;
  f32x4 v = *(const f32x4*)&s[off];
  ushort4 o; o.x = f2b(v[0]); o.y = f2b(v[1]); o.z = f2b(v[2]); o.w = f2b(v[3]);
  *(ushort4*)&dst[f] = o;
}

__global__ __launch_bounds__(256) void convLora(
    const float* a0, const float* a1, const float* a2, const float* a3, const float* a4,
    const float* b0, const float* b1, const float* b2, const float* b3, const float* b4,
    const float* l0, const float* l1, const float* l2, const float* l3, const float* l4,
    u16* __restrict__ laD, u16* __restrict__ lbD, float* __restrict__ llD) {
  long f = ((long)blockIdx.x * 256 + threadIdx.x) << 2;
  if (f < 327680) {            // 5 x 65536 la
    int sel = (int)(f >> 16); long off = f & 65535;
    const float* s = sel == 0 ? a0 : sel == 1 ? a1 : sel == 2 ? a2 : sel == 3 ? a3 : a4;
    f32x4 v = *(const f32x4*)&s[off];
    ushort4 o; o.x = f2b(v[0]); o.y = f2b(v[1]); o.z = f2b(v[2]); o.w = f2b(v[3]);
    *(ushort4*)&laD[f] = o;
  } else if (f < 655360) {     // 5 x 65536 lb
    long g = f - 327680;
    int sel = (int)(g >> 16); long off = g & 65535;
    const float* s = sel == 0 ? b0 : sel == 1 ? b1 : sel == 2 ? b2 : sel == 3 ? b3 : b4;
    f32x4 v = *(const f32x4*)&s[off];
    ushort4 o; o.x = f2b(v[0]); o.y = f2b(v[1]); o.z = f2b(v[2]); o.w = f2b(v[3]);
    *(ushort4*)&lbD[g] = o;
  } else if (f < 660480) {     // 5 x 1024 ll (f32 copy)
    long g = f - 655360;
    int sel = (int)(g >> 10); long off = g & 1023;
    const float* s = sel == 0 ? l0 : sel == 1 ? l1 : sel == 2 ? l2 : sel == 3 ? l3 : l4;
    *(f32x4*)&llD[g] = *(const f32x4*)&s[off];
  }
}

// ---------------- token shift prep: lerpx, xB, dxB (all bf16) ----------------
__global__ __launch_bounds__(256) void prep(const float* __restrict__ x, const float* __restrict__ xw,
                                            u16* __restrict__ lerpx, u16* __restrict__ xB,
                                            u16* __restrict__ dxB) {
  long f = ((long)blockIdx.x * 256 + threadIdx.x) << 2;
  int d = (int)(f & (DD - 1));
  int m = (int)(f >> 10);
  int t = m & (TTOK - 1);
  f32x4 xv = *(const f32x4*)&x[f];
  f32x4 xm = {};
  if (t > 0) xm = *(const f32x4*)&x[f - DD];
  f32x4 xwv = *(const f32x4*)&xw[d];
  f32x4 dx = xm - xv;
  f32x4 lp = xv + dx * xwv;
  ushort4 o; o.x = f2b(lp[0]); o.y = f2b(lp[1]); o.z = f2b(lp[2]); o.w = f2b(lp[3]);
  *(ushort4*)&lerpx[f] = o;
  ushort4 ox; ox.x = f2b(xv[0]); ox.y = f2b(xv[1]); ox.z = f2b(xv[2]); ox.w = f2b(xv[3]);
  *(ushort4*)&xB[f] = ox;
  ushort4 od; od.x = f2b(dx[0]); od.y = f2b(dx[1]); od.z = f2b(dx[2]); od.w = f2b(dx[3]);
  *(ushort4*)&dxB[f] = od;
}

// ---------------- bf16 MFMA GEMM, m97-style: BK=64, global_load_lds, swizzled LDS ----
// C[m][n] = sum_k A[m][k]*B[n][k].   blockIdx.x -> M tile (A-panel sharers co-XCD).
// EPI: 0 = store f32; 1 = store bf16(tanh); 2 = z-epilogue bf16(x + dx*(ll+acc));
//      3 = store f32 exp(-exp(ll+acc)); 4 = store bf16
template<int BM, int BN, int EPI>
__launch_bounds__(256)
__global__ void gemm2(const u16* __restrict__ Ab, long sAz,
                      const u16* __restrict__ Bb, long sBz,
                      void* __restrict__ Ob, long sOz,
                      const float* __restrict__ llb,
                      const u16* __restrict__ xB,
                      const u16* __restrict__ dxB,
                      int M, int N, int K) {
  __shared__ __align__(16) u16 As[BM * 64];
  __shared__ __align__(16) u16 Bs[BN * 64];
  const int z = blockIdx.z;
  const u16* A = Ab + (long)z * sAz;
  const u16* Bw = Bb + (long)z * sBz;
  const int m0 = blockIdx.x * BM;
  const int n0 = blockIdx.y * BN;
  const int tid = threadIdx.x;
  const int l = tid & 63;
  const int wv = tid >> 6;
  constexpr int WM = BM / 2, WN = BN / 2;
  constexpr int FM = WM / 16, FN = WN / 16;
  const int wm0 = (wv >> 1) * WM, wn0 = (wv & 1) * WN;
  const int lrow = l & 15, lk = (l >> 4) * 8;
  constexpr int GA = BM / 32, GB = BN / 32;   // 16B gloads per thread per tile
  int gA[GA], gB[GB];
#pragma unroll
  for (int q = 0; q < GA; ++q) {
    int d = (q * 256 + tid) * 16;
    int bb = swz(d);
    gA[q] = (m0 + (bb >> 7)) * K + ((bb & 127) >> 1);
  }
#pragma unroll
  for (int q = 0; q < GB; ++q) {
    int d = (q * 256 + tid) * 16;
    int bb = swz(d);
    gB[q] = (n0 + (bb >> 7)) * K + ((bb & 127) >> 1);
  }
  int aOff[FM][2], bOff[FN][2];
#pragma unroll
  for (int m = 0; m < FM; ++m)
#pragma unroll
    for (int kk = 0; kk < 2; ++kk)
      aOff[m][kk] = swz(((wm0 + m * 16 + lrow) << 7) + (kk << 6) + (lk << 1));
#pragma unroll
  for (int n = 0; n < FN; ++n)
#pragma unroll
    for (int kk = 0; kk < 2; ++kk)
      bOff[n][kk] = swz(((wn0 + n * 16 + lrow) << 7) + (kk << 6) + (lk << 1));
  f32x4 acc[FM][FN] = {};
  for (int k0 = 0; k0 < K; k0 += 64) {
    __syncthreads();
#pragma unroll
    for (int q = 0; q < GA; ++q)
      gload16(&A[(long)gA[q] + k0], (u16*)((char*)As + (q * 256 + tid) * 16));
#pragma unroll
    for (int q = 0; q < GB; ++q)
      gload16(&Bw[(long)gB[q] + k0], (u16*)((char*)Bs + (q * 256 + tid) * 16));
    __syncthreads();   // drains vmcnt -> LDS tile complete
#pragma unroll
    for (int kk = 0; kk < 2; ++kk) {
      s16x8 af[FM], bfr[FN];
#pragma unroll
      for (int m = 0; m < FM; ++m) af[m] = *(const s16x8*)((const char*)As + aOff[m][kk]);
#pragma unroll
      for (int n = 0; n < FN; ++n) bfr[n] = *(const s16x8*)((const char*)Bs + bOff[n][kk]);
#pragma unroll
      for (int m = 0; m < FM; ++m)
#pragma unroll
        for (int n = 0; n < FN; ++n)
          acc[m][n] = __builtin_amdgcn_mfma_f32_16x16x32_bf16(af[m], bfr[n], acc[m][n], 0, 0, 0);
    }
  }
#pragma unroll
  for (int m = 0; m < FM; ++m) {
#pragma unroll
    for (int n = 0; n < FN; ++n) {
      const int j = n0 + wn0 + n * 16 + lrow;
#pragma unroll
      for (int q = 0; q < 4; ++q) {
        const int i = m0 + wm0 + m * 16 + (l >> 4) * 4 + q;
        const long off = (long)i * N + j;
        float v = acc[m][n][q];
        if constexpr (EPI == 0) {
          ((float*)Ob + (long)z * sOz)[off] = v;
        } else if constexpr (EPI == 1) {
          ((u16*)Ob + (long)z * sOz)[off] = f2b(tanhf(v));
        } else if constexpr (EPI == 2) {
          float val = b2f(xB[off]) + b2f(dxB[off]) * (llb[(long)z * N + j] + v);
          ((u16*)Ob + (long)z * sOz)[off] = f2b(val);
        } else if constexpr (EPI == 3) {
          ((float*)Ob + (long)z * sOz)[off] = expf(-expf(llb[j] + v));
        } else {
          ((u16*)Ob + (long)z * sOz)[off] = f2b(v);
        }
      }
    }
  }
}

// ---------------- S1: chunk-local WKV scan, f32-LDS staged, 8 waves, LDS y-combine --
// r,k reg-staged global->f32 LDS (unpack ONCE); w f32 and v bf16 via global_load_lds.
// Wave q owns state rows [8q,8q+8) as f32x2[4] (v_pk_fma path, no per-step unpack).
// Per-step partial y combined across waves via ds_add_f32 into Ys tile; one bf16
// writeout per block. Wave0: rtil+A-product; wave1: u-term.
__global__ __launch_bounds__(512) void scan_local(
    const u16* __restrict__ rP, const u16* __restrict__ kP,
    const u16* __restrict__ vP, const float* __restrict__ wP,
    const float* __restrict__ uP, u16* __restrict__ ysB,
    u16* __restrict__ rtil, float* __restrict__ SL, float* __restrict__ AC) {
  __shared__ __align__(16) float Rf[64 * 64];   // 16KB
  __shared__ __align__(16) float Kf[64 * 64];   // 16KB
  __shared__ __align__(16) float Wf[64 * 64];   // 16KB
  __shared__ __align__(16) float Ys[64 * 64];   // 16KB
  __shared__ __align__(16) u16 Vs[64 * 64];     // 8KB
  const int bhc = blockIdx.x;
  const int c = bhc & (NCH - 1), h = (bhc >> 4) & (NH - 1), b = bhc >> 8;
  const int tid = threadIdx.x;
  const int j = tid & 63;
  const int qu = tid >> 6;                 // wave id 0..7
  const long base0 = ((long)(b * TTOK + c * CLEN) << 10) + h * HD;
  const int st = tid >> 3, sjo = (tid & 7) * 8;   // staging coords: 8 elems/thread
  // ---- stage v (bf16) and w (f32) via global_load_lds ----
  gload16(&vP[base0 + (long)st * DD + sjo], (u16*)Vs + tid * 8);
#pragma unroll
  for (int q = 0; q < 2; ++q) {
    int cidx = q * 512 + tid;
    int t = cidx >> 4, off = (cidx & 15) * 4;
    __builtin_amdgcn_global_load_lds((const AS1 u32*)&wP[base0 + (long)t * DD + off],
                                     (AS3 u32*)((float*)Wf + cidx * 4), 16, 0, 0);
  }
  // ---- reg-stage r,k: load bf16x8, convert once, write f32 LDS; zero Ys ----
  {
    s16x8 rv = *(const s16x8*)&rP[base0 + (long)st * DD + sjo];
    s16x8 kv = *(const s16x8*)&kP[base0 + (long)st * DD + sjo];
    f32x4 r0, r1, k0, k1;
#pragma unroll
    for (int e = 0; e < 4; ++e) {
      r0[e] = b2f((u16)rv[e]); r1[e] = b2f((u16)rv[e + 4]);
      k0[e] = b2f((u16)kv[e]); k1[e] = b2f((u16)kv[e + 4]);
    }
    *(f32x4*)&Rf[st * 64 + sjo] = r0; *(f32x4*)&Rf[st * 64 + sjo + 4] = r1;
    *(f32x4*)&Kf[st * 64 + sjo] = k0; *(f32x4*)&Kf[st * 64 + sjo + 4] = k1;
    f32x4 zz = {};
    *(f32x4*)&Ys[tid * 8] = zz; *(f32x4*)&Ys[tid * 8 + 4] = zz;
  }
  __syncthreads();                          // all staging complete
  const int so = qu * 8;
  f32x2 s2[4] = {};
  float Aj = 1.f;
  const float uj = (qu == 1) ? uP[h * HD + j] : 0.f;
  long base = base0;
  for (int tt = 0; tt < CLEN; ++tt) {
    const int ro = tt * 64 + so;
    const f32x4 r03 = *(const f32x4*)&Rf[ro];     // wave-uniform -> broadcast
    const f32x4 r47 = *(const f32x4*)&Rf[ro + 4];
    const f32x4 k03 = *(const f32x4*)&Kf[ro];
    const f32x4 k47 = *(const f32x4*)&Kf[ro + 4];
    const f32x4 w03 = *(const f32x4*)&Wf[ro];
    const f32x4 w47 = *(const f32x4*)&Wf[ro + 4];
    const float vj = b2f(Vs[tt * 64 + j]);
    const f32x2 vj2 = {vj, vj};
    f32x2 y2 = {0.f, 0.f};
    {
      const f32x2 rp = {r03[0], r03[1]}, kp = {k03[0], k03[1]}, wp = {w03[0], w03[1]};
      y2 = __builtin_elementwise_fma(rp, s2[0], y2);
      s2[0] = __builtin_elementwise_fma(wp, s2[0], kp * vj2);
    }
    {
      const f32x2 rp = {r03[2], r03[3]}, kp = {k03[2], k03[3]}, wp = {w03[2], w03[3]};
      y2 = __builtin_elementwise_fma(rp, s2[1], y2);
      s2[1] = __builtin_elementwise_fma(wp, s2[1], kp * vj2);
    }
    {
      const f32x2 rp = {r47[0], r47[1]}, kp = {k47[0], k47[1]}, wp = {w47[0], w47[1]};
      y2 = __builtin_elementwise_fma(rp, s2[2], y2);
      s2[2] = __builtin_elementwise_fma(wp, s2[2], kp * vj2);
    }
    {
      const f32x2 rp = {r47[2], r47[3]}, kp = {k47[2], k47[3]}, wp = {w47[2], w47[3]};
      y2 = __builtin_elementwise_fma(rp, s2[3], y2);
      s2[3] = __builtin_elementwise_fma(wp, s2[3], kp * vj2);
    }
    float y = y2[0] + y2[1];
    if (qu == 0) {                           // rtil + decay product
      const float rj = Rf[tt * 64 + j];
      rtil[base + j] = f2b(rj * Aj);         // r_t * A_{t-1}
      Aj *= Wf[tt * 64 + j];
    } else if (qu == 1) {                    // u-term -> fold into this wave's add
      const float rj = Rf[tt * 64 + j];
      const float kj = Kf[tt * 64 + j];
      float al = rj * uj * kj;
#pragma unroll
      for (int msk = 1; msk < 64; msk <<= 1) al += __shfl_xor(al, msk, 64);
      y = fmaf(al, vj, y);
    }
    atomicAdd(&Ys[tt * 64 + j], y);          // ds_add_f32, no return
    base += DD;
  }
#pragma unroll
  for (int e = 0; e < 4; ++e) {
    SL[((long)bhc * 64 + so + 2 * e) * 64 + j] = s2[e][0];
    SL[((long)bhc * 64 + so + 2 * e + 1) * 64 + j] = s2[e][1];
  }
  if (qu == 0) AC[(long)bhc * 64 + j] = Aj;
  __syncthreads();                          // all ds_add complete
  {
    const f32x4 a = *(const f32x4*)&Ys[st * 64 + sjo];
    const f32x4 bq = *(const f32x4*)&Ys[st * 64 + sjo + 4];
    s16x8 o;
#pragma unroll
    for (int e = 0; e < 4; ++e) { o[e] = (short)f2b(a[e]); o[e + 4] = (short)f2b(bq[e]); }
    *(s16x8*)&ysB[base0 + (long)st * DD + sjo] = o;
  }
}

// ---------------- S2a: propagate chunk-boundary states; overwrite SL[c] with S_in(c) ----------------
__global__ __launch_bounds__(256) void scan_prop(
    float* __restrict__ SL, const float* __restrict__ AC,
    const float* __restrict__ initS, float* __restrict__ st1) {
  const int bh = blockIdx.x >> 2;          // 64 bh
  const int jq = blockIdx.x & 3;
  const int h = bh & (NH - 1);
  const int i = threadIdx.x >> 2;
  const int jo = jq * 16 + (threadIdx.x & 3) * 4;
  f32x4 sin4 = *(const f32x4*)(initS + ((long)h * 64 + i) * 64 + jo);
  for (int cc = 0; cc < NCH; ++cc) {
    const long bhc = (long)bh * NCH + cc;
    f32x4* slp = (f32x4*)(SL + (bhc * 64 + i) * 64 + jo);
    const float Ai = AC[bhc * 64 + i];
    f32x4 sl = *slp;
    *slp = sin4;                           // S_in(c) for S2b
    sin4 = Ai * sin4 + sl;
  }
  *(f32x4*)(st1 + ((long)bh * 64 + i) * 64 + jo) = sin4;
}

// ---------------- S2b: cross-chunk correction ysC = rtil @ S_in (store, f32) -------
__global__ __launch_bounds__(256) void scan_corr(
    const float* __restrict__ SL, const u16* __restrict__ rtil, float* __restrict__ ysC) {
  __shared__ __align__(16) float S[64 * 64];
  const int bhc = blockIdx.x;
  const int c = bhc & (NCH - 1), h = (bhc >> 4) & (NH - 1), b = bhc >> 8;
  const int tid = threadIdx.x;
  const f32x4* sp = (const f32x4*)(SL + (long)bhc * 4096);
  for (int q = tid; q < 1024; q += 256) ((f32x4*)S)[q] = sp[q];
  __syncthreads();
  const int t = tid >> 2, jg = (tid & 3) * 16;
  const long base = ((long)(b * TTOK + c * CLEN + t) * DD) + h * HD;
  f32x4 yacc[4] = {};
  const u16* rp = rtil + base;
#pragma unroll 8
  for (int i = 0; i < 64; ++i) {
    const float r = b2f(rp[i]);
    const f32x4* srow = (const f32x4*)&S[i * 64 + jg];
#pragma unroll
    for (int e = 0; e < 4; ++e) yacc[e] += r * srow[e];
  }
  f32x4* yp = (f32x4*)(ysC + base + jg);
#pragma unroll
  for (int e = 0; e < 4; ++e) yp[e] = yacc[e];
}

// ---------------- GroupNorm(hd=64) * SiLU(g) -> o (bf16) ----------------
__global__ __launch_bounds__(256) void ln_silu(
    const u16* __restrict__ ysB, const float* __restrict__ ysC,
    const u16* __restrict__ gP,
    const float* __restrict__ lnw, const float* __restrict__ lnb,
    u16* __restrict__ oB) {
  const int ridx = blockIdx.x * 4 + (threadIdx.x >> 6);   // (token*16 + h)
  const int lane = threadIdx.x & 63;
  const long basem = (long)ridx * 64;
  const float y = b2f(ysB[basem + lane]) + ysC[basem + lane];
  float su = y, sq = y * y;
#pragma unroll
  for (int msk = 1; msk < 64; msk <<= 1) {
    su += __shfl_xor(su, msk, 64);
    sq += __shfl_xor(sq, msk, 64);
  }
  const float mean = su * (1.f / 64.f);
  const float var = sq * (1.f / 64.f) - mean * mean;
  const float rs = rsqrtf(var + 1e-5f);
  const float g = b2f(gP[basem + lane]);
  const float silu = g / (1.f + expf(-g));
  const float val = silu * ((y - mean) * rs * lnw[lane] + lnb[lane]);
  oB[basem + lane] = f2b(val);
}

// ---------------- launcher ----------------
extern "C" void kernel_launch(void* const* d_in, const int* in_sizes, int n_in,
                              void* d_out, int out_size, void* d_ws, size_t ws_size,
                              hipStream_t stream) {
  const float* x   = (const float*)d_in[0];
  const float* xw  = (const float*)d_in[1];
  const float* rW  = (const float*)d_in[2];
  const float* kW  = (const float*)d_in[3];
  const float* vW  = (const float*)d_in[4];
  const float* gW  = (const float*)d_in[5];
  const float* r_la = (const float*)d_in[6],  *r_lb = (const float*)d_in[7],  *r_ll = (const float*)d_in[8];
  const float* k_la = (const float*)d_in[9],  *k_lb = (const float*)d_in[10], *k_ll = (const float*)d_in[11];
  const float* v_la = (const float*)d_in[12], *v_lb = (const float*)d_in[13], *v_ll = (const float*)d_in[14];
  const float* g_la = (const float*)d_in[15], *g_lb = (const float*)d_in[16], *g_ll = (const float*)d_in[17];
  const float* d_la = (const float*)d_in[18], *d_lb = (const float*)d_in[19], *d_ll = (const float*)d_in[20];
  const float* lnw = (const float*)d_in[21];
  const float* lnb = (const float*)d_in[22];
  const float* oW  = (const float*)d_in[23];
  const float* initS = (const float*)d_in[24];
  const float* uP  = (const float*)d_in[25];
  float* out = (float*)d_out;

  // workspace layout (~183 MB)
  char* ws = (char*)d_ws;
  u16*   W_all  = (u16*)(ws + 0);                  // [5][1024][1024] bf16 (r,k,v,g,o)
  u16*   la_all = (u16*)(ws + 10485760);           // [5][64][1024]
  u16*   lb_all = (u16*)(ws + 11141120);           // [5][1024][64]
  float* ll_all = (float*)(ws + 11796480);         // [5][1024]
  u16*   lerpx  = (u16*)(ws + 11816960);           // [4096][1024] bf16 (dead after lora1)
  u16*   xB     = (u16*)(ws + 20205568);           // [4096][1024] bf16 (dead after z-stage2)
  u16*   dxB    = (u16*)(ws + 28594176);           // [4096][1024] bf16 (dead after z-stage2)
  u16*   t1_all = (u16*)(ws + 36982784);           // [5][4096][64] bf16
  u16*   z_all  = (u16*)(ws + 39604224);           // [5][4096][1024] bf16 (dead after projections)
  u16*   rkvg   = (u16*)(ws + 81547264);           // [4][4096][1024] bf16
  float* wbuf   = (float*)(ws + 115101696);        // [4096][1024] f32 (dead after scan_local)
  u16*   rtil   = (u16*)(ws + 131878912);          // [4096][1024] bf16
  float* SL     = (float*)(ws + 140267520);        // [1024][64][64] f32
  float* AC     = (float*)(ws + 157044736);        // [1024][64] f32
  u16*   ysB    = (u16*)(ws + 157306880);          // [4096][1024] bf16 combined intra-chunk y
  u16*   oB     = (u16*)(ws + 174084096);          // [4096][1024] bf16
  float* ysC    = (float*)(ws + 115101696);        // overlay: wbuf (f32 correction)

  convW<<<5120, 256, 0, stream>>>(rW, kW, vW, gW, oW, W_all);
  convLora<<<645, 256, 0, stream>>>(r_la, k_la, v_la, g_la, d_la,
                                    r_lb, k_lb, v_lb, g_lb, d_lb,
                                    r_ll, k_ll, v_ll, g_ll, d_ll,
                                    la_all, lb_all, ll_all);
  prep<<<4096, 256, 0, stream>>>(x, xw, lerpx, xB, dxB);

  // LoRA stage 1 (all 5): t1 = tanh(lerpx @ la^T)      [4096 x 64]
  gemm2<64, 64, 1><<<dim3(64, 1, 5), 256, 0, stream>>>(
      lerpx, 0L, la_all, 65536L, (void*)t1_all, 262144L, nullptr, nullptr, nullptr, MT, 64, 1024);
  // LoRA stage 2 (all 5): z = bf16(x + dx*(ll + t1 @ lb^T))   [4096 x 1024]
  gemm2<128, 128, 2><<<dim3(32, 8, 5), 256, 0, stream>>>(
      t1_all, 262144L, lb_all, 65536L, (void*)z_all, 4194304L, ll_all, xB, dxB, MT, 1024, 64);
  // d-outer stage 1: t2 = tanh(z_d @ d_la^T)
  gemm2<64, 64, 1><<<dim3(64, 1, 1), 256, 0, stream>>>(
      z_all + 4L * 4194304, 0L, la_all + 4L * 65536, 0L, (void*)t1_all, 0L, nullptr, nullptr, nullptr, MT, 64, 1024);
  // d-outer stage 2: w = exp(-exp(d_ll + t2 @ d_lb^T))  (f32)
  gemm2<128, 128, 3><<<dim3(32, 8, 1), 256, 0, stream>>>(
      t1_all, 0L, lb_all + 4L * 65536, 0L, (void*)wbuf, 0L, ll_all + 4096, nullptr, nullptr, MT, 1024, 64);
  // projections r,k,v,g = z @ W^T (bf16 out)
  gemm2<128, 128, 4><<<dim3(32, 8, 4), 256, 0, stream>>>(
      z_all, 4194304L, W_all, 1048576L, (void*)rkvg, 4194304L, nullptr, nullptr, nullptr, MT, 1024, 1024);

  // chunked WKV scan
  scan_local<<<1024, 512, 0, stream>>>(rkvg, rkvg + 4194304L, rkvg + 2L * 4194304, wbuf,
                                       uP, ysB, rtil, SL, AC);
  scan_prop<<<256, 256, 0, stream>>>(SL, AC, initS, out + 4194304);
  scan_corr<<<1024, 256, 0, stream>>>(SL, rtil, ysC);

  // o = silu(g) * groupnorm(y); out = o @ oW^T
  ln_silu<<<16384, 256, 0, stream>>>(ysB, ysC, rkvg + 3L * 4194304, lnw, lnb, oB);
  gemm2<128, 128, 0><<<dim3(32, 8, 1), 256, 0, stream>>>(
      oB, 0L, W_all + 4L * 1048576, 0L, (void*)out, 0L, nullptr, nullptr, nullptr, MT, 1024, 1024);
}

// Round 8
// 357.481 us; speedup vs baseline: 1.4361x; 1.4361x over previous
//
#include <hip/hip_runtime.h>
#include <hip/hip_bf16.h>

typedef unsigned short u16;
typedef unsigned int u32;
typedef __attribute__((ext_vector_type(2))) float f32x2;
typedef __attribute__((ext_vector_type(4))) float f32x4;
typedef __attribute__((ext_vector_type(8))) short s16x8;

#define AS1 __attribute__((address_space(1)))
#define AS3 __attribute__((address_space(3)))

#define NB 4
#define TTOK 1024
#define DD 1024
#define NH 16
#define HD 64
#define MT 4096      // B*T tokens
#define NCH 16       // chunks per (b,h)
#define CLEN 64      // chunk length

static __device__ __forceinline__ float b2f(u16 u) {
  union { unsigned int u; float f; } c; c.u = ((unsigned int)u) << 16; return c.f;
}
static __device__ __forceinline__ u16 f2b(float f) {
  union { float f; unsigned int u; } c; c.f = f;
  return (u16)((c.u + 0x7fffu + ((c.u >> 16) & 1u)) >> 16);
}
// direct global->LDS async copy, 16B per lane
static __device__ __forceinline__ void gload16(const u16* g, u16* l) {
  __builtin_amdgcn_global_load_lds((const AS1 u32*)g, (AS3 u32*)l, 16, 0, 0);
}
// LDS byte-offset swizzle (involution, keeps 16B chunks intact)
static __device__ __forceinline__ int swz(int lin) {
  return lin ^ (((lin >> 9) & 3) << 5) ^ (((lin >> 7) & 1) << 4);
}

// ---------------- weight conversion / packing ----------------
__global__ __launch_bounds__(256) void convW(const float* __restrict__ s0, const float* __restrict__ s1,
                                             const float* __restrict__ s2, const float* __restrict__ s3,
                                             const float* __restrict__ s4, u16* __restrict__ dst) {
  long f = ((long)blockIdx.x * 256 + threadIdx.x) << 2;   // 5 * 1048576 elems
  int sel = (int)(f >> 20);
  const float* s = sel == 0 ? s0 : sel == 1 ? s1 : sel == 2 ? s2 : sel == 3 ? s3 : s4;
  long off = f & 1048575;
  f32x4 v = *(const f32x4*)&s[off];
  ushort4 o; o.x = f2b(v[0]); o.y = f2b(v[1]); o.z = f2b(v[2]); o.w = f2b(v[3]);
  *(ushort4*)&dst[f] = o;
}

__global__ __launch_bounds__(256) void convLora(
    const float* a0, const float* a1, const float* a2, const float* a3, const float* a4,
    const float* b0, const float* b1, const float* b2, const float* b3, const float* b4,
    const float* l0, const float* l1, const float* l2, const float* l3, const float* l4,
    u16* __restrict__ laD, u16* __restrict__ lbD, float* __restrict__ llD) {
  long f = ((long)blockIdx.x * 256 + threadIdx.x) << 2;
  if (f < 327680) {            // 5 x 65536 la
    int sel = (int)(f >> 16); long off = f & 65535;
    const float* s = sel == 0 ? a0 : sel == 1 ? a1 : sel == 2 ? a2 : sel == 3 ? a3 : a4;
    f32x4 v = *(const f32x4*)&s[off];
    ushort4 o; o.x = f2b(v[0]); o.y = f2b(v[1]); o.z = f2b(v[2]); o.w = f2b(v[3]);
    *(ushort4*)&laD[f] = o;
  } else if (f < 655360) {     // 5 x 65536 lb
    long g = f - 327680;
    int sel = (int)(g >> 16); long off = g & 65535;
    const float* s = sel == 0 ? b0 : sel == 1 ? b1 : sel == 2 ? b2 : sel == 3 ? b3 : b4;
    f32x4 v = *(const f32x4*)&s[off];
    ushort4 o; o.x = f2b(v[0]); o.y = f2b(v[1]); o.z = f2b(v[2]); o.w = f2b(v[3]);
    *(ushort4*)&lbD[g] = o;
  } else if (f < 660480) {     // 5 x 1024 ll (f32 copy)
    long g = f - 655360;
    int sel = (int)(g >> 10); long off = g & 1023;
    const float* s = sel == 0 ? l0 : sel == 1 ? l1 : sel == 2 ? l2 : sel == 3 ? l3 : l4;
    *(f32x4*)&llD[g] = *(const f32x4*)&s[off];
  }
}

// ---------------- token shift prep: lerpx, xB, dxB (all bf16) ----------------
__global__ __launch_bounds__(256) void prep(const float* __restrict__ x, const float* __restrict__ xw,
                                            u16* __restrict__ lerpx, u16* __restrict__ xB,
                                            u16* __restrict__ dxB) {
  long f = ((long)blockIdx.x * 256 + threadIdx.x) << 2;
  int d = (int)(f & (DD - 1));
  int m = (int)(f >> 10);
  int t = m & (TTOK - 1);
  f32x4 xv = *(const f32x4*)&x[f];
  f32x4 xm = {};
  if (t > 0) xm = *(const f32x4*)&x[f - DD];
  f32x4 xwv = *(const f32x4*)&xw[d];
  f32x4 dx = xm - xv;
  f32x4 lp = xv + dx * xwv;
  ushort4 o; o.x = f2b(lp[0]); o.y = f2b(lp[1]); o.z = f2b(lp[2]); o.w = f2b(lp[3]);
  *(ushort4*)&lerpx[f] = o;
  ushort4 ox; ox.x = f2b(xv[0]); ox.y = f2b(xv[1]); ox.z = f2b(xv[2]); ox.w = f2b(xv[3]);
  *(ushort4*)&xB[f] = ox;
  ushort4 od; od.x = f2b(dx[0]); od.y = f2b(dx[1]); od.z = f2b(dx[2]); od.w = f2b(dx[3]);
  *(ushort4*)&dxB[f] = od;
}

// ---------------- bf16 MFMA GEMM, m97-style: BK=64, global_load_lds, swizzled LDS ----
// C[m][n] = sum_k A[m][k]*B[n][k].   blockIdx.x -> M tile (A-panel sharers co-XCD).
// EPI: 0 = store f32; 1 = store bf16(tanh); 2 = z-epilogue bf16(x + dx*(ll+acc));
//      3 = store f32 exp(-exp(ll+acc)); 4 = store bf16
template<int BM, int BN, int EPI>
__launch_bounds__(256)
__global__ void gemm2(const u16* __restrict__ Ab, long sAz,
                      const u16* __restrict__ Bb, long sBz,
                      void* __restrict__ Ob, long sOz,
                      const float* __restrict__ llb,
                      const u16* __restrict__ xB,
                      const u16* __restrict__ dxB,
                      int M, int N, int K) {
  __shared__ __align__(16) u16 As[BM * 64];
  __shared__ __align__(16) u16 Bs[BN * 64];
  const int z = blockIdx.z;
  const u16* A = Ab + (long)z * sAz;
  const u16* Bw = Bb + (long)z * sBz;
  const int m0 = blockIdx.x * BM;
  const int n0 = blockIdx.y * BN;
  const int tid = threadIdx.x;
  const int l = tid & 63;
  const int wv = tid >> 6;
  constexpr int WM = BM / 2, WN = BN / 2;
  constexpr int FM = WM / 16, FN = WN / 16;
  const int wm0 = (wv >> 1) * WM, wn0 = (wv & 1) * WN;
  const int lrow = l & 15, lk = (l >> 4) * 8;
  constexpr int GA = BM / 32, GB = BN / 32;   // 16B gloads per thread per tile
  int gA[GA], gB[GB];
#pragma unroll
  for (int q = 0; q < GA; ++q) {
    int d = (q * 256 + tid) * 16;
    int bb = swz(d);
    gA[q] = (m0 + (bb >> 7)) * K + ((bb & 127) >> 1);
  }
#pragma unroll
  for (int q = 0; q < GB; ++q) {
    int d = (q * 256 + tid) * 16;
    int bb = swz(d);
    gB[q] = (n0 + (bb >> 7)) * K + ((bb & 127) >> 1);
  }
  int aOff[FM][2], bOff[FN][2];
#pragma unroll
  for (int m = 0; m < FM; ++m)
#pragma unroll
    for (int kk = 0; kk < 2; ++kk)
      aOff[m][kk] = swz(((wm0 + m * 16 + lrow) << 7) + (kk << 6) + (lk << 1));
#pragma unroll
  for (int n = 0; n < FN; ++n)
#pragma unroll
    for (int kk = 0; kk < 2; ++kk)
      bOff[n][kk] = swz(((wn0 + n * 16 + lrow) << 7) + (kk << 6) + (lk << 1));
  f32x4 acc[FM][FN] = {};
  for (int k0 = 0; k0 < K; k0 += 64) {
    __syncthreads();
#pragma unroll
    for (int q = 0; q < GA; ++q)
      gload16(&A[(long)gA[q] + k0], (u16*)((char*)As + (q * 256 + tid) * 16));
#pragma unroll
    for (int q = 0; q < GB; ++q)
      gload16(&Bw[(long)gB[q] + k0], (u16*)((char*)Bs + (q * 256 + tid) * 16));
    __syncthreads();   // drains vmcnt -> LDS tile complete
#pragma unroll
    for (int kk = 0; kk < 2; ++kk) {
      s16x8 af[FM], bfr[FN];
#pragma unroll
      for (int m = 0; m < FM; ++m) af[m] = *(const s16x8*)((const char*)As + aOff[m][kk]);
#pragma unroll
      for (int n = 0; n < FN; ++n) bfr[n] = *(const s16x8*)((const char*)Bs + bOff[n][kk]);
#pragma unroll
      for (int m = 0; m < FM; ++m)
#pragma unroll
        for (int n = 0; n < FN; ++n)
          acc[m][n] = __builtin_amdgcn_mfma_f32_16x16x32_bf16(af[m], bfr[n], acc[m][n], 0, 0, 0);
    }
  }
#pragma unroll
  for (int m = 0; m < FM; ++m) {
#pragma unroll
    for (int n = 0; n < FN; ++n) {
      const int j = n0 + wn0 + n * 16 + lrow;
#pragma unroll
      for (int q = 0; q < 4; ++q) {
        const int i = m0 + wm0 + m * 16 + (l >> 4) * 4 + q;
        const long off = (long)i * N + j;
        float v = acc[m][n][q];
        if constexpr (EPI == 0) {
          ((float*)Ob + (long)z * sOz)[off] = v;
        } else if constexpr (EPI == 1) {
          ((u16*)Ob + (long)z * sOz)[off] = f2b(tanhf(v));
        } else if constexpr (EPI == 2) {
          float val = b2f(xB[off]) + b2f(dxB[off]) * (llb[(long)z * N + j] + v);
          ((u16*)Ob + (long)z * sOz)[off] = f2b(val);
        } else if constexpr (EPI == 3) {
          ((float*)Ob + (long)z * sOz)[off] = expf(-expf(llb[j] + v));
        } else {
          ((u16*)Ob + (long)z * sOz)[off] = f2b(v);
        }
      }
    }
  }
}

// ---------------- S1: chunk-local WKV scan, column-split waves, shfl y-reduce -------
// Wave q owns j-columns [8q,8q+8); lane l: column j = 8q+(l&7), state rows
// [8g, 8g+8) where g = l>>3. y_t[j] completed by intra-wave shfl_xor over
// bits 3..5 — no cross-wave combine, no atomics. r/k unpacked bf16->f32 ONCE at
// staging; inner loop is pure v_pk_fma. Ys and rtil collect in LDS (one writer
// per (t,j)), bulk bf16 store at end.
__global__ __launch_bounds__(512) void scan_local(
    const u16* __restrict__ rP, const u16* __restrict__ kP,
    const u16* __restrict__ vP, const float* __restrict__ wP,
    const float* __restrict__ uP, u16* __restrict__ ysB,
    u16* __restrict__ rtil, float* __restrict__ SL, float* __restrict__ AC) {
  __shared__ __align__(16) float Rf[64 * 64];   // 16KB
  __shared__ __align__(16) float Kf[64 * 64];   // 16KB
  __shared__ __align__(16) float Wf[64 * 64];   // 16KB
  __shared__ __align__(16) float Ys[64 * 64];   // 16KB
  __shared__ __align__(16) u16 Vs[64 * 64];     // 8KB
  __shared__ __align__(16) u16 Rt[64 * 64];     // 8KB
  const int bhc = blockIdx.x;
  const int c = bhc & (NCH - 1), h = (bhc >> 4) & (NH - 1), b = bhc >> 8;
  const int tid = threadIdx.x;
  const int l = tid & 63;
  const int qu = tid >> 6;                 // wave id 0..7
  const int g = l >> 3;                    // state-row group
  const int j = qu * 8 + (l & 7);          // owned column
  const long base0 = ((long)(b * TTOK + c * CLEN) << 10) + h * HD;
  const int st = tid >> 3, sjo = (tid & 7) * 8;   // staging coords: 8 elems/thread
  // ---- stage v (bf16) and w (f32) via global_load_lds ----
  gload16(&vP[base0 + (long)st * DD + sjo], (u16*)Vs + tid * 8);
#pragma unroll
  for (int q = 0; q < 2; ++q) {
    int cidx = q * 512 + tid;
    int t = cidx >> 4, off = (cidx & 15) * 4;
    __builtin_amdgcn_global_load_lds((const AS1 u32*)&wP[base0 + (long)t * DD + off],
                                     (AS3 u32*)((float*)Wf + cidx * 4), 16, 0, 0);
  }
  // ---- reg-stage r,k: load bf16x8, convert once, write f32 LDS ----
  {
    s16x8 rv = *(const s16x8*)&rP[base0 + (long)st * DD + sjo];
    s16x8 kv = *(const s16x8*)&kP[base0 + (long)st * DD + sjo];
    f32x4 r0, r1, k0, k1;
#pragma unroll
    for (int e = 0; e < 4; ++e) {
      r0[e] = b2f((u16)rv[e]); r1[e] = b2f((u16)rv[e + 4]);
      k0[e] = b2f((u16)kv[e]); k1[e] = b2f((u16)kv[e + 4]);
    }
    *(f32x4*)&Rf[st * 64 + sjo] = r0; *(f32x4*)&Rf[st * 64 + sjo + 4] = r1;
    *(f32x4*)&Kf[st * 64 + sjo] = k0; *(f32x4*)&Kf[st * 64 + sjo + 4] = k1;
  }
  __syncthreads();                          // all staging complete
  // u for this lane's 8 state rows
  f32x2 u2[4];
#pragma unroll
  for (int e = 0; e < 4; ++e) u2[e] = *(const f32x2*)&uP[h * HD + 8 * g + 2 * e];
  f32x2 s2[4] = {};
  float Aj = 1.f;
  for (int tt = 0; tt < CLEN; ++tt) {
    const int ro = tt * 64 + 8 * g;
    const f32x4 r03 = *(const f32x4*)&Rf[ro];
    const f32x4 r47 = *(const f32x4*)&Rf[ro + 4];
    const f32x4 k03 = *(const f32x4*)&Kf[ro];
    const f32x4 k47 = *(const f32x4*)&Kf[ro + 4];
    const f32x4 w03 = *(const f32x4*)&Wf[ro];
    const f32x4 w47 = *(const f32x4*)&Wf[ro + 4];
    const float vj = b2f(Vs[tt * 64 + j]);
    const f32x2 vj2 = {vj, vj};
    f32x2 y2 = {0.f, 0.f};
    {
      const f32x2 rp = {r03[0], r03[1]}, kp = {k03[0], k03[1]}, wp = {w03[0], w03[1]};
      const f32x2 uk = u2[0] * kp;
      y2 = __builtin_elementwise_fma(rp, __builtin_elementwise_fma(uk, vj2, s2[0]), y2);
      s2[0] = __builtin_elementwise_fma(wp, s2[0], kp * vj2);
    }
    {
      const f32x2 rp = {r03[2], r03[3]}, kp = {k03[2], k03[3]}, wp = {w03[2], w03[3]};
      const f32x2 uk = u2[1] * kp;
      y2 = __builtin_elementwise_fma(rp, __builtin_elementwise_fma(uk, vj2, s2[1]), y2);
      s2[1] = __builtin_elementwise_fma(wp, s2[1], kp * vj2);
    }
    {
      const f32x2 rp = {r47[0], r47[1]}, kp = {k47[0], k47[1]}, wp = {w47[0], w47[1]};
      const f32x2 uk = u2[2] * kp;
      y2 = __builtin_elementwise_fma(rp, __builtin_elementwise_fma(uk, vj2, s2[2]), y2);
      s2[2] = __builtin_elementwise_fma(wp, s2[2], kp * vj2);
    }
    {
      const f32x2 rp = {r47[2], r47[3]}, kp = {k47[2], k47[3]}, wp = {w47[2], w47[3]};
      const f32x2 uk = u2[3] * kp;
      y2 = __builtin_elementwise_fma(rp, __builtin_elementwise_fma(uk, vj2, s2[3]), y2);
      s2[3] = __builtin_elementwise_fma(wp, s2[3], kp * vj2);
    }
    float y = y2[0] + y2[1];
    y += __shfl_xor(y, 8, 64);
    y += __shfl_xor(y, 16, 64);
    y += __shfl_xor(y, 32, 64);             // all lanes: full column sum
    if ((l & 56) == 0) {                    // g==0 lanes: one writer per (t,j)
      const float rj = Rf[tt * 64 + j];
      Rt[tt * 64 + j] = f2b(rj * Aj);       // r_t * A_{t-1}
      Aj *= Wf[tt * 64 + j];
      Ys[tt * 64 + j] = y;
    }
  }
#pragma unroll
  for (int e = 0; e < 4; ++e) {
    SL[((long)bhc * 64 + 8 * g + 2 * e) * 64 + j] = s2[e][0];
    SL[((long)bhc * 64 + 8 * g + 2 * e + 1) * 64 + j] = s2[e][1];
  }
  if ((l & 56) == 0) AC[(long)bhc * 64 + j] = Aj;
  __syncthreads();                          // Ys/Rt tiles complete
  {
    const f32x4 a = *(const f32x4*)&Ys[st * 64 + sjo];
    const f32x4 bq = *(const f32x4*)&Ys[st * 64 + sjo + 4];
    s16x8 o;
#pragma unroll
    for (int e = 0; e < 4; ++e) { o[e] = (short)f2b(a[e]); o[e + 4] = (short)f2b(bq[e]); }
    *(s16x8*)&ysB[base0 + (long)st * DD + sjo] = o;
    *(s16x8*)&rtil[base0 + (long)st * DD + sjo] = *(const s16x8*)&Rt[st * 64 + sjo];
  }
}

// ---------------- S2a: propagate chunk-boundary states; overwrite SL[c] with S_in(c) ----------------
__global__ __launch_bounds__(256) void scan_prop(
    float* __restrict__ SL, const float* __restrict__ AC,
    const float* __restrict__ initS, float* __restrict__ st1) {
  const int bh = blockIdx.x >> 2;          // 64 bh
  const int jq = blockIdx.x & 3;
  const int h = bh & (NH - 1);
  const int i = threadIdx.x >> 2;
  const int jo = jq * 16 + (threadIdx.x & 3) * 4;
  f32x4 sin4 = *(const f32x4*)(initS + ((long)h * 64 + i) * 64 + jo);
  for (int cc = 0; cc < NCH; ++cc) {
    const long bhc = (long)bh * NCH + cc;
    f32x4* slp = (f32x4*)(SL + (bhc * 64 + i) * 64 + jo);
    const float Ai = AC[bhc * 64 + i];
    f32x4 sl = *slp;
    *slp = sin4;                           // S_in(c) for S2b
    sin4 = Ai * sin4 + sl;
  }
  *(f32x4*)(st1 + ((long)bh * 64 + i) * 64 + jo) = sin4;
}

// ---------------- S2b: cross-chunk correction ysC = rtil @ S_in (store, f32) -------
__global__ __launch_bounds__(256) void scan_corr(
    const float* __restrict__ SL, const u16* __restrict__ rtil, float* __restrict__ ysC) {
  __shared__ __align__(16) float S[64 * 64];
  const int bhc = blockIdx.x;
  const int c = bhc & (NCH - 1), h = (bhc >> 4) & (NH - 1), b = bhc >> 8;
  const int tid = threadIdx.x;
  const f32x4* sp = (const f32x4*)(SL + (long)bhc * 4096);
  for (int q = tid; q < 1024; q += 256) ((f32x4*)S)[q] = sp[q];
  __syncthreads();
  const int t = tid >> 2, jg = (tid & 3) * 16;
  const long base = ((long)(b * TTOK + c * CLEN + t) * DD) + h * HD;
  f32x4 yacc[4] = {};
  const u16* rp = rtil + base;
#pragma unroll 8
  for (int i = 0; i < 64; ++i) {
    const float r = b2f(rp[i]);
    const f32x4* srow = (const f32x4*)&S[i * 64 + jg];
#pragma unroll
    for (int e = 0; e < 4; ++e) yacc[e] += r * srow[e];
  }
  f32x4* yp = (f32x4*)(ysC + base + jg);
#pragma unroll
  for (int e = 0; e < 4; ++e) yp[e] = yacc[e];
}

// ---------------- GroupNorm(hd=64) * SiLU(g) -> o (bf16) ----------------
__global__ __launch_bounds__(256) void ln_silu(
    const u16* __restrict__ ysB, const float* __restrict__ ysC,
    const u16* __restrict__ gP,
    const float* __restrict__ lnw, const float* __restrict__ lnb,
    u16* __restrict__ oB) {
  const int ridx = blockIdx.x * 4 + (threadIdx.x >> 6);   // (token*16 + h)
  const int lane = threadIdx.x & 63;
  const long basem = (long)ridx * 64;
  const float y = b2f(ysB[basem + lane]) + ysC[basem + lane];
  float su = y, sq = y * y;
#pragma unroll
  for (int msk = 1; msk < 64; msk <<= 1) {
    su += __shfl_xor(su, msk, 64);
    sq += __shfl_xor(sq, msk, 64);
  }
  const float mean = su * (1.f / 64.f);
  const float var = sq * (1.f / 64.f) - mean * mean;
  const float rs = rsqrtf(var + 1e-5f);
  const float g = b2f(gP[basem + lane]);
  const float silu = g / (1.f + expf(-g));
  const float val = silu * ((y - mean) * rs * lnw[lane] + lnb[lane]);
  oB[basem + lane] = f2b(val);
}

// ---------------- launcher ----------------
extern "C" void kernel_launch(void* const* d_in, const int* in_sizes, int n_in,
                              void* d_out, int out_size, void* d_ws, size_t ws_size,
                              hipStream_t stream) {
  const float* x   = (const float*)d_in[0];
  const float* xw  = (const float*)d_in[1];
  const float* rW  = (const float*)d_in[2];
  const float* kW  = (const float*)d_in[3];
  const float* vW  = (const float*)d_in[4];
  const float* gW  = (const float*)d_in[5];
  const float* r_la = (const float*)d_in[6],  *r_lb = (const float*)d_in[7],  *r_ll = (const float*)d_in[8];
  const float* k_la = (const float*)d_in[9],  *k_lb = (const float*)d_in[10], *k_ll = (const float*)d_in[11];
  const float* v_la = (const float*)d_in[12], *v_lb = (const float*)d_in[13], *v_ll = (const float*)d_in[14];
  const float* g_la = (const float*)d_in[15], *g_lb = (const float*)d_in[16], *g_ll = (const float*)d_in[17];
  const float* d_la = (const float*)d_in[18], *d_lb = (const float*)d_in[19], *d_ll = (const float*)d_in[20];
  const float* lnw = (const float*)d_in[21];
  const float* lnb = (const float*)d_in[22];
  const float* oW  = (const float*)d_in[23];
  const float* initS = (const float*)d_in[24];
  const float* uP  = (const float*)d_in[25];
  float* out = (float*)d_out;

  // workspace layout (~183 MB)
  char* ws = (char*)d_ws;
  u16*   W_all  = (u16*)(ws + 0);                  // [5][1024][1024] bf16 (r,k,v,g,o)
  u16*   la_all = (u16*)(ws + 10485760);           // [5][64][1024]
  u16*   lb_all = (u16*)(ws + 11141120);           // [5][1024][64]
  float* ll_all = (float*)(ws + 11796480);         // [5][1024]
  u16*   lerpx  = (u16*)(ws + 11816960);           // [4096][1024] bf16 (dead after lora1)
  u16*   xB     = (u16*)(ws + 20205568);           // [4096][1024] bf16 (dead after z-stage2)
  u16*   dxB    = (u16*)(ws + 28594176);           // [4096][1024] bf16 (dead after z-stage2)
  u16*   t1_all = (u16*)(ws + 36982784);           // [5][4096][64] bf16
  u16*   z_all  = (u16*)(ws + 39604224);           // [5][4096][1024] bf16 (dead after projections)
  u16*   rkvg   = (u16*)(ws + 81547264);           // [4][4096][1024] bf16
  float* wbuf   = (float*)(ws + 115101696);        // [4096][1024] f32 (dead after scan_local)
  u16*   rtil   = (u16*)(ws + 131878912);          // [4096][1024] bf16
  float* SL     = (float*)(ws + 140267520);        // [1024][64][64] f32
  float* AC     = (float*)(ws + 157044736);        // [1024][64] f32
  u16*   ysB    = (u16*)(ws + 157306880);          // [4096][1024] bf16 combined intra-chunk y
  u16*   oB     = (u16*)(ws + 174084096);          // [4096][1024] bf16
  float* ysC    = (float*)(ws + 115101696);        // overlay: wbuf (f32 correction)

  convW<<<5120, 256, 0, stream>>>(rW, kW, vW, gW, oW, W_all);
  convLora<<<645, 256, 0, stream>>>(r_la, k_la, v_la, g_la, d_la,
                                    r_lb, k_lb, v_lb, g_lb, d_lb,
                                    r_ll, k_ll, v_ll, g_ll, d_ll,
                                    la_all, lb_all, ll_all);
  prep<<<4096, 256, 0, stream>>>(x, xw, lerpx, xB, dxB);

  // LoRA stage 1 (all 5): t1 = tanh(lerpx @ la^T)      [4096 x 64]
  gemm2<64, 64, 1><<<dim3(64, 1, 5), 256, 0, stream>>>(
      lerpx, 0L, la_all, 65536L, (void*)t1_all, 262144L, nullptr, nullptr, nullptr, MT, 64, 1024);
  // LoRA stage 2 (all 5): z = bf16(x + dx*(ll + t1 @ lb^T))   [4096 x 1024]
  gemm2<128, 128, 2><<<dim3(32, 8, 5), 256, 0, stream>>>(
      t1_all, 262144L, lb_all, 65536L, (void*)z_all, 4194304L, ll_all, xB, dxB, MT, 1024, 64);
  // d-outer stage 1: t2 = tanh(z_d @ d_la^T)
  gemm2<64, 64, 1><<<dim3(64, 1, 1), 256, 0, stream>>>(
      z_all + 4L * 4194304, 0L, la_all + 4L * 65536, 0L, (void*)t1_all, 0L, nullptr, nullptr, nullptr, MT, 64, 1024);
  // d-outer stage 2: w = exp(-exp(d_ll + t2 @ d_lb^T))  (f32)
  gemm2<128, 128, 3><<<dim3(32, 8, 1), 256, 0, stream>>>(
      t1_all, 0L, lb_all + 4L * 65536, 0L, (void*)wbuf, 0L, ll_all + 4096, nullptr, nullptr, MT, 1024, 64);
  // projections r,k,v,g = z @ W^T (bf16 out)
  gemm2<128, 128, 4><<<dim3(32, 8, 4), 256, 0, stream>>>(
      z_all, 4194304L, W_all, 1048576L, (void*)rkvg, 4194304L, nullptr, nullptr, nullptr, MT, 1024, 1024);

  // chunked WKV scan
  scan_local<<<1024, 512, 0, stream>>>(rkvg, rkvg + 4194304L, rkvg + 2L * 4194304, wbuf,
                                       uP, ysB, rtil, SL, AC);
  scan_prop<<<256, 256, 0, stream>>>(SL, AC, initS, out + 4194304);
  scan_corr<<<1024, 256, 0, stream>>>(SL, rtil, ysC);

  // o = silu(g) * groupnorm(y); out = o @ oW^T
  ln_silu<<<16384, 256, 0, stream>>>(ysB, ysC, rkvg + 3L * 4194304, lnw, lnb, oB);
  gemm2<128, 128, 0><<<dim3(32, 8, 1), 256, 0, stream>>>(
      oB, 0L, W_all + 4L * 1048576, 0L, (void*)out, 0L, nullptr, nullptr, nullptr, MT, 1024, 1024);
}

// Round 9
// 354.998 us; speedup vs baseline: 1.4461x; 1.0070x over previous
//
#include <hip/hip_runtime.h>
#include <hip/hip_bf16.h>

typedef unsigned short u16;
typedef unsigned int u32;
typedef __attribute__((ext_vector_type(2))) float f32x2;
typedef __attribute__((ext_vector_type(4))) float f32x4;
typedef __attribute__((ext_vector_type(8))) short s16x8;

#define AS1 __attribute__((address_space(1)))
#define AS3 __attribute__((address_space(3)))

#define NB 4
#define TTOK 1024
#define DD 1024
#define NH 16
#define HD 64
#define MT 4096      // B*T tokens
#define NCH 16       // chunks per (b,h)
#define CLEN 64      // chunk length

static __device__ __forceinline__ float b2f(u16 u) {
  union { unsigned int u; float f; } c; c.u = ((unsigned int)u) << 16; return c.f;
}
static __device__ __forceinline__ u16 f2b(float f) {
  union { float f; unsigned int u; } c; c.f = f;
  return (u16)((c.u + 0x7fffu + ((c.u >> 16) & 1u)) >> 16);
}
// direct global->LDS async copy, 16B per lane
static __device__ __forceinline__ void gload16(const u16* g, u16* l) {
  __builtin_amdgcn_global_load_lds((const AS1 u32*)g, (AS3 u32*)l, 16, 0, 0);
}
// LDS byte-offset swizzle (involution, keeps 16B chunks intact)
static __device__ __forceinline__ int swz(int lin) {
  return lin ^ (((lin >> 9) & 3) << 5) ^ (((lin >> 7) & 1) << 4);
}

// ---------------- weight conversion / packing ----------------
__global__ __launch_bounds__(256) void convW(const float* __restrict__ s0, const float* __restrict__ s1,
                                             const float* __restrict__ s2, const float* __restrict__ s3,
                                             const float* __restrict__ s4, u16* __restrict__ dst) {
  long f = ((long)blockIdx.x * 256 + threadIdx.x) << 2;   // 5 * 1048576 elems
  int sel = (int)(f >> 20);
  const float* s = sel == 0 ? s0 : sel == 1 ? s1 : sel == 2 ? s2 : sel == 3 ? s3 : s4;
  long off = f & 1048575;
  f32x4 v = *(const f32x4*)&s[off];
  ushort4 o; o.x = f2b(v[0]); o.y = f2b(v[1]); o.z = f2b(v[2]); o.w = f2b(v[3]);
  *(ushort4*)&dst[f] = o;
}

__global__ __launch_bounds__(256) void convLora(
    const float* a0, const float* a1, const float* a2, const float* a3, const float* a4,
    const float* b0, const float* b1, const float* b2, const float* b3, const float* b4,
    const float* l0, const float* l1, const float* l2, const float* l3, const float* l4,
    u16* __restrict__ laD, u16* __restrict__ lbD, float* __restrict__ llD) {
  long f = ((long)blockIdx.x * 256 + threadIdx.x) << 2;
  if (f < 327680) {            // 5 x 65536 la
    int sel = (int)(f >> 16); long off = f & 65535;
    const float* s = sel == 0 ? a0 : sel == 1 ? a1 : sel == 2 ? a2 : sel == 3 ? a3 : a4;
    f32x4 v = *(const f32x4*)&s[off];
    ushort4 o; o.x = f2b(v[0]); o.y = f2b(v[1]); o.z = f2b(v[2]); o.w = f2b(v[3]);
    *(ushort4*)&laD[f] = o;
  } else if (f < 655360) {     // 5 x 65536 lb
    long g = f - 327680;
    int sel = (int)(g >> 16); long off = g & 65535;
    const float* s = sel == 0 ? b0 : sel == 1 ? b1 : sel == 2 ? b2 : sel == 3 ? b3 : b4;
    f32x4 v = *(const f32x4*)&s[off];
    ushort4 o; o.x = f2b(v[0]); o.y = f2b(v[1]); o.z = f2b(v[2]); o.w = f2b(v[3]);
    *(ushort4*)&lbD[g] = o;
  } else if (f < 660480) {     // 5 x 1024 ll (f32 copy)
    long g = f - 655360;
    int sel = (int)(g >> 10); long off = g & 1023;
    const float* s = sel == 0 ? l0 : sel == 1 ? l1 : sel == 2 ? l2 : sel == 3 ? l3 : l4;
    *(f32x4*)&llD[g] = *(const f32x4*)&s[off];
  }
}

// ---------------- token shift prep: lerpx, xB, dxB (all bf16) ----------------
__global__ __launch_bounds__(256) void prep(const float* __restrict__ x, const float* __restrict__ xw,
                                            u16* __restrict__ lerpx, u16* __restrict__ xB,
                                            u16* __restrict__ dxB) {
  long f = ((long)blockIdx.x * 256 + threadIdx.x) << 2;
  int d = (int)(f & (DD - 1));
  int m = (int)(f >> 10);
  int t = m & (TTOK - 1);
  f32x4 xv = *(const f32x4*)&x[f];
  f32x4 xm = {};
  if (t > 0) xm = *(const f32x4*)&x[f - DD];
  f32x4 xwv = *(const f32x4*)&xw[d];
  f32x4 dx = xm - xv;
  f32x4 lp = xv + dx * xwv;
  ushort4 o; o.x = f2b(lp[0]); o.y = f2b(lp[1]); o.z = f2b(lp[2]); o.w = f2b(lp[3]);
  *(ushort4*)&lerpx[f] = o;
  ushort4 ox; ox.x = f2b(xv[0]); ox.y = f2b(xv[1]); ox.z = f2b(xv[2]); ox.w = f2b(xv[3]);
  *(ushort4*)&xB[f] = ox;
  ushort4 od; od.x = f2b(dx[0]); od.y = f2b(dx[1]); od.z = f2b(dx[2]); od.w = f2b(dx[3]);
  *(ushort4*)&dxB[f] = od;
}

// ---------------- bf16 MFMA GEMM, m97-style: BK=64, global_load_lds, swizzled LDS ----
// C[m][n] = sum_k A[m][k]*B[n][k].   blockIdx.x -> M tile (A-panel sharers co-XCD).
// EPI: 0 = store f32; 1 = store bf16(tanh); 2 = z-epilogue bf16(x + dx*(ll+acc));
//      3 = store f32 exp(-exp(ll+acc)); 4 = store bf16
template<int BM, int BN, int EPI>
__launch_bounds__(256)
__global__ void gemm2(const u16* __restrict__ Ab, long sAz,
                      const u16* __restrict__ Bb, long sBz,
                      void* __restrict__ Ob, long sOz,
                      const float* __restrict__ llb,
                      const u16* __restrict__ xB,
                      const u16* __restrict__ dxB,
                      int M, int N, int K) {
  __shared__ __align__(16) u16 As[BM * 64];
  __shared__ __align__(16) u16 Bs[BN * 64];
  const int z = blockIdx.z;
  const u16* A = Ab + (long)z * sAz;
  const u16* Bw = Bb + (long)z * sBz;
  const int m0 = blockIdx.x * BM;
  const int n0 = blockIdx.y * BN;
  const int tid = threadIdx.x;
  const int l = tid & 63;
  const int wv = tid >> 6;
  constexpr int WM = BM / 2, WN = BN / 2;
  constexpr int FM = WM / 16, FN = WN / 16;
  const int wm0 = (wv >> 1) * WM, wn0 = (wv & 1) * WN;
  const int lrow = l & 15, lk = (l >> 4) * 8;
  constexpr int GA = BM / 32, GB = BN / 32;   // 16B gloads per thread per tile
  int gA[GA], gB[GB];
#pragma unroll
  for (int q = 0; q < GA; ++q) {
    int d = (q * 256 + tid) * 16;
    int bb = swz(d);
    gA[q] = (m0 + (bb >> 7)) * K + ((bb & 127) >> 1);
  }
#pragma unroll
  for (int q = 0; q < GB; ++q) {
    int d = (q * 256 + tid) * 16;
    int bb = swz(d);
    gB[q] = (n0 + (bb >> 7)) * K + ((bb & 127) >> 1);
  }
  int aOff[FM][2], bOff[FN][2];
#pragma unroll
  for (int m = 0; m < FM; ++m)
#pragma unroll
    for (int kk = 0; kk < 2; ++kk)
      aOff[m][kk] = swz(((wm0 + m * 16 + lrow) << 7) + (kk << 6) + (lk << 1));
#pragma unroll
  for (int n = 0; n < FN; ++n)
#pragma unroll
    for (int kk = 0; kk < 2; ++kk)
      bOff[n][kk] = swz(((wn0 + n * 16 + lrow) << 7) + (kk << 6) + (lk << 1));
  f32x4 acc[FM][FN] = {};
  for (int k0 = 0; k0 < K; k0 += 64) {
    __syncthreads();
#pragma unroll
    for (int q = 0; q < GA; ++q)
      gload16(&A[(long)gA[q] + k0], (u16*)((char*)As + (q * 256 + tid) * 16));
#pragma unroll
    for (int q = 0; q < GB; ++q)
      gload16(&Bw[(long)gB[q] + k0], (u16*)((char*)Bs + (q * 256 + tid) * 16));
    __syncthreads();   // drains vmcnt -> LDS tile complete
#pragma unroll
    for (int kk = 0; kk < 2; ++kk) {
      s16x8 af[FM], bfr[FN];
#pragma unroll
      for (int m = 0; m < FM; ++m) af[m] = *(const s16x8*)((const char*)As + aOff[m][kk]);
#pragma unroll
      for (int n = 0; n < FN; ++n) bfr[n] = *(const s16x8*)((const char*)Bs + bOff[n][kk]);
#pragma unroll
      for (int m = 0; m < FM; ++m)
#pragma unroll
        for (int n = 0; n < FN; ++n)
          acc[m][n] = __builtin_amdgcn_mfma_f32_16x16x32_bf16(af[m], bfr[n], acc[m][n], 0, 0, 0);
    }
  }
#pragma unroll
  for (int m = 0; m < FM; ++m) {
#pragma unroll
    for (int n = 0; n < FN; ++n) {
      const int j = n0 + wn0 + n * 16 + lrow;
#pragma unroll
      for (int q = 0; q < 4; ++q) {
        const int i = m0 + wm0 + m * 16 + (l >> 4) * 4 + q;
        const long off = (long)i * N + j;
        float v = acc[m][n][q];
        if constexpr (EPI == 0) {
          ((float*)Ob + (long)z * sOz)[off] = v;
        } else if constexpr (EPI == 1) {
          ((u16*)Ob + (long)z * sOz)[off] = f2b(tanhf(v));
        } else if constexpr (EPI == 2) {
          float val = b2f(xB[off]) + b2f(dxB[off]) * (llb[(long)z * N + j] + v);
          ((u16*)Ob + (long)z * sOz)[off] = f2b(val);
        } else if constexpr (EPI == 3) {
          ((float*)Ob + (long)z * sOz)[off] = expf(-expf(llb[j] + v));
        } else {
          ((u16*)Ob + (long)z * sOz)[off] = f2b(v);
        }
      }
    }
  }
}

// ---------------- S1: chunk-local WKV scan, broadcast reads + register partials ----
// Wave w owns state rows [8w,8w+8) for ALL j (lane = j). r/k/w reads per step are
// wave-uniform ds_read_b128 broadcasts (minimal LDS traffic). u folds per-row.
// Per-step partial y kept in y8[8] registers; every 8 steps the 8 wave-strips are
// combined through a 16KB LDS buffer by 512 threads and stored bf16 to ysB.
// Wave0 additionally produces rtil (into LDS tile, bulk-stored) and the A product.
__global__ __launch_bounds__(512) void scan_local(
    const u16* __restrict__ rP, const u16* __restrict__ kP,
    const u16* __restrict__ vP, const float* __restrict__ wP,
    const float* __restrict__ uP, u16* __restrict__ ysB,
    u16* __restrict__ rtil, float* __restrict__ SL, float* __restrict__ AC) {
  __shared__ __align__(16) float Rf[64 * 64];   // 16KB
  __shared__ __align__(16) float Kf[64 * 64];   // 16KB
  __shared__ __align__(16) float Wf[64 * 64];   // 16KB
  __shared__ __align__(16) float Y8[8][8][64];  // 16KB  [wave][t'][j]
  __shared__ __align__(16) u16 Vs[64 * 64];     // 8KB
  __shared__ __align__(16) u16 Rt[64 * 64];     // 8KB
  const int bhc = blockIdx.x;
  const int c = bhc & (NCH - 1), h = (bhc >> 4) & (NH - 1), b = bhc >> 8;
  const int tid = threadIdx.x;
  const int l = tid & 63;                  // j column
  const int wv = tid >> 6;                 // wave id 0..7 -> state rows [8wv,8wv+8)
  const long base0 = ((long)(b * TTOK + c * CLEN) << 10) + h * HD;
  const int st = tid >> 3, sjo = (tid & 7) * 8;   // staging coords: 8 elems/thread
  // ---- stage v (bf16) and w (f32) via global_load_lds ----
  gload16(&vP[base0 + (long)st * DD + sjo], (u16*)Vs + tid * 8);
#pragma unroll
  for (int q = 0; q < 2; ++q) {
    int cidx = q * 512 + tid;
    int t = cidx >> 4, off = (cidx & 15) * 4;
    __builtin_amdgcn_global_load_lds((const AS1 u32*)&wP[base0 + (long)t * DD + off],
                                     (AS3 u32*)((float*)Wf + cidx * 4), 16, 0, 0);
  }
  // ---- reg-stage r,k: load bf16x8, convert once, write f32 LDS ----
  {
    s16x8 rv = *(const s16x8*)&rP[base0 + (long)st * DD + sjo];
    s16x8 kv = *(const s16x8*)&kP[base0 + (long)st * DD + sjo];
    f32x4 r0, r1, k0, k1;
#pragma unroll
    for (int e = 0; e < 4; ++e) {
      r0[e] = b2f((u16)rv[e]); r1[e] = b2f((u16)rv[e + 4]);
      k0[e] = b2f((u16)kv[e]); k1[e] = b2f((u16)kv[e + 4]);
    }
    *(f32x4*)&Rf[st * 64 + sjo] = r0; *(f32x4*)&Rf[st * 64 + sjo + 4] = r1;
    *(f32x4*)&Kf[st * 64 + sjo] = k0; *(f32x4*)&Kf[st * 64 + sjo + 4] = k1;
  }
  __syncthreads();                          // all staging complete
  // u for this wave's 8 state rows (wave-uniform)
  f32x2 u2[4];
#pragma unroll
  for (int e = 0; e < 4; ++e) u2[e] = *(const f32x2*)&uP[h * HD + 8 * wv + 2 * e];
  f32x2 s2[4] = {};
  float Aj = 1.f;
  for (int t0 = 0; t0 < CLEN; t0 += 8) {
    float y8[8];
#pragma unroll
    for (int q = 0; q < 8; ++q) {
      const int tt = t0 + q;
      const int ro = tt * 64 + 8 * wv;
      const f32x4 rA = *(const f32x4*)&Rf[ro];      // wave-uniform -> broadcast
      const f32x4 rB = *(const f32x4*)&Rf[ro + 4];
      const f32x4 kA = *(const f32x4*)&Kf[ro];
      const f32x4 kB = *(const f32x4*)&Kf[ro + 4];
      const f32x4 wA = *(const f32x4*)&Wf[ro];
      const f32x4 wB = *(const f32x4*)&Wf[ro + 4];
      const float vj = b2f(Vs[tt * 64 + l]);
      const f32x2 vj2 = {vj, vj};
      f32x2 y2 = {0.f, 0.f};
      {
        const f32x2 rp = {rA[0], rA[1]}, kp = {kA[0], kA[1]}, wp = {wA[0], wA[1]};
        const f32x2 kv = kp * vj2;
        y2 = __builtin_elementwise_fma(rp, __builtin_elementwise_fma(u2[0], kv, s2[0]), y2);
        s2[0] = __builtin_elementwise_fma(wp, s2[0], kv);
      }
      {
        const f32x2 rp = {rA[2], rA[3]}, kp = {kA[2], kA[3]}, wp = {wA[2], wA[3]};
        const f32x2 kv = kp * vj2;
        y2 = __builtin_elementwise_fma(rp, __builtin_elementwise_fma(u2[1], kv, s2[1]), y2);
        s2[1] = __builtin_elementwise_fma(wp, s2[1], kv);
      }
      {
        const f32x2 rp = {rB[0], rB[1]}, kp = {kB[0], kB[1]}, wp = {wB[0], wB[1]};
        const f32x2 kv = kp * vj2;
        y2 = __builtin_elementwise_fma(rp, __builtin_elementwise_fma(u2[2], kv, s2[2]), y2);
        s2[2] = __builtin_elementwise_fma(wp, s2[2], kv);
      }
      {
        const f32x2 rp = {rB[2], rB[3]}, kp = {kB[2], kB[3]}, wp = {wB[2], wB[3]};
        const f32x2 kv = kp * vj2;
        y2 = __builtin_elementwise_fma(rp, __builtin_elementwise_fma(u2[3], kv, s2[3]), y2);
        s2[3] = __builtin_elementwise_fma(wp, s2[3], kv);
      }
      y8[q] = y2[0] + y2[1];
      if (wv == 0) {                       // rtil + decay product (per-lane j)
        const float rj = Rf[tt * 64 + l];
        Rt[tt * 64 + l] = f2b(rj * Aj);    // r_t * A_{t-1}
        Aj *= Wf[tt * 64 + l];
      }
    }
    // dump wave strip, combine across the 8 waves, store bf16
#pragma unroll
    for (int q = 0; q < 8; ++q) Y8[wv][q][l] = y8[q];
    __syncthreads();
    {
      float acc = Y8[0][wv][l];            // thread -> (t' = wv, j = l)
#pragma unroll
      for (int w2 = 1; w2 < 8; ++w2) acc += Y8[w2][wv][l];
      ysB[base0 + (long)(t0 + wv) * DD + l] = f2b(acc);
    }
    __syncthreads();
  }
  // state out
#pragma unroll
  for (int e = 0; e < 4; ++e) {
    SL[((long)bhc * 64 + 8 * wv + 2 * e) * 64 + l] = s2[e][0];
    SL[((long)bhc * 64 + 8 * wv + 2 * e + 1) * 64 + l] = s2[e][1];
  }
  if (wv == 0) AC[(long)bhc * 64 + l] = Aj;
  __syncthreads();                          // Rt tile complete
  *(s16x8*)&rtil[base0 + (long)st * DD + sjo] = *(const s16x8*)&Rt[st * 64 + sjo];
}

// ---------------- S2a: propagate chunk-boundary states; overwrite SL[c] with S_in(c) ----------------
__global__ __launch_bounds__(256) void scan_prop(
    float* __restrict__ SL, const float* __restrict__ AC,
    const float* __restrict__ initS, float* __restrict__ st1) {
  const int bh = blockIdx.x >> 2;          // 64 bh
  const int jq = blockIdx.x & 3;
  const int h = bh & (NH - 1);
  const int i = threadIdx.x >> 2;
  const int jo = jq * 16 + (threadIdx.x & 3) * 4;
  f32x4 sin4 = *(const f32x4*)(initS + ((long)h * 64 + i) * 64 + jo);
  for (int cc = 0; cc < NCH; ++cc) {
    const long bhc = (long)bh * NCH + cc;
    f32x4* slp = (f32x4*)(SL + (bhc * 64 + i) * 64 + jo);
    const float Ai = AC[bhc * 64 + i];
    f32x4 sl = *slp;
    *slp = sin4;                           // S_in(c) for S2b
    sin4 = Ai * sin4 + sl;
  }
  *(f32x4*)(st1 + ((long)bh * 64 + i) * 64 + jo) = sin4;
}

// ---------------- S2b: cross-chunk correction ysC = rtil @ S_in (store, f32) -------
__global__ __launch_bounds__(256) void scan_corr(
    const float* __restrict__ SL, const u16* __restrict__ rtil, float* __restrict__ ysC) {
  __shared__ __align__(16) float S[64 * 64];
  const int bhc = blockIdx.x;
  const int c = bhc & (NCH - 1), h = (bhc >> 4) & (NH - 1), b = bhc >> 8;
  const int tid = threadIdx.x;
  const f32x4* sp = (const f32x4*)(SL + (long)bhc * 4096);
  for (int q = tid; q < 1024; q += 256) ((f32x4*)S)[q] = sp[q];
  __syncthreads();
  const int t = tid >> 2, jg = (tid & 3) * 16;
  const long base = ((long)(b * TTOK + c * CLEN + t) * DD) + h * HD;
  f32x4 yacc[4] = {};
  const u16* rp = rtil + base;
#pragma unroll 8
  for (int i = 0; i < 64; ++i) {
    const float r = b2f(rp[i]);
    const f32x4* srow = (const f32x4*)&S[i * 64 + jg];
#pragma unroll
    for (int e = 0; e < 4; ++e) yacc[e] += r * srow[e];
  }
  f32x4* yp = (f32x4*)(ysC + base + jg);
#pragma unroll
  for (int e = 0; e < 4; ++e) yp[e] = yacc[e];
}

// ---------------- GroupNorm(hd=64) * SiLU(g) -> o (bf16) ----------------
__global__ __launch_bounds__(256) void ln_silu(
    const u16* __restrict__ ysB, const float* __restrict__ ysC,
    const u16* __restrict__ gP,
    const float* __restrict__ lnw, const float* __restrict__ lnb,
    u16* __restrict__ oB) {
  const int ridx = blockIdx.x * 4 + (threadIdx.x >> 6);   // (token*16 + h)
  const int lane = threadIdx.x & 63;
  const long basem = (long)ridx * 64;
  const float y = b2f(ysB[basem + lane]) + ysC[basem + lane];
  float su = y, sq = y * y;
#pragma unroll
  for (int msk = 1; msk < 64; msk <<= 1) {
    su += __shfl_xor(su, msk, 64);
    sq += __shfl_xor(sq, msk, 64);
  }
  const float mean = su * (1.f / 64.f);
  const float var = sq * (1.f / 64.f) - mean * mean;
  const float rs = rsqrtf(var + 1e-5f);
  const float g = b2f(gP[basem + lane]);
  const float silu = g / (1.f + expf(-g));
  const float val = silu * ((y - mean) * rs * lnw[lane] + lnb[lane]);
  oB[basem + lane] = f2b(val);
}

// ---------------- launcher ----------------
extern "C" void kernel_launch(void* const* d_in, const int* in_sizes, int n_in,
                              void* d_out, int out_size, void* d_ws, size_t ws_size,
                              hipStream_t stream) {
  const float* x   = (const float*)d_in[0];
  const float* xw  = (const float*)d_in[1];
  const float* rW  = (const float*)d_in[2];
  const float* kW  = (const float*)d_in[3];
  const float* vW  = (const float*)d_in[4];
  const float* gW  = (const float*)d_in[5];
  const float* r_la = (const float*)d_in[6],  *r_lb = (const float*)d_in[7],  *r_ll = (const float*)d_in[8];
  const float* k_la = (const float*)d_in[9],  *k_lb = (const float*)d_in[10], *k_ll = (const float*)d_in[11];
  const float* v_la = (const float*)d_in[12], *v_lb = (const float*)d_in[13], *v_ll = (const float*)d_in[14];
  const float* g_la = (const float*)d_in[15], *g_lb = (const float*)d_in[16], *g_ll = (const float*)d_in[17];
  const float* d_la = (const float*)d_in[18], *d_lb = (const float*)d_in[19], *d_ll = (const float*)d_in[20];
  const float* lnw = (const float*)d_in[21];
  const float* lnb = (const float*)d_in[22];
  const float* oW  = (const float*)d_in[23];
  const float* initS = (const float*)d_in[24];
  const float* uP  = (const float*)d_in[25];
  float* out = (float*)d_out;

  // workspace layout (~183 MB)
  char* ws = (char*)d_ws;
  u16*   W_all  = (u16*)(ws + 0);                  // [5][1024][1024] bf16 (r,k,v,g,o)
  u16*   la_all = (u16*)(ws + 10485760);           // [5][64][1024]
  u16*   lb_all = (u16*)(ws + 11141120);           // [5][1024][64]
  float* ll_all = (float*)(ws + 11796480);         // [5][1024]
  u16*   lerpx  = (u16*)(ws + 11816960);           // [4096][1024] bf16 (dead after lora1)
  u16*   xB     = (u16*)(ws + 20205568);           // [4096][1024] bf16 (dead after z-stage2)
  u16*   dxB    = (u16*)(ws + 28594176);           // [4096][1024] bf16 (dead after z-stage2)
  u16*   t1_all = (u16*)(ws + 36982784);           // [5][4096][64] bf16
  u16*   z_all  = (u16*)(ws + 39604224);           // [5][4096][1024] bf16 (dead after projections)
  u16*   rkvg   = (u16*)(ws + 81547264);           // [4][4096][1024] bf16
  float* wbuf   = (float*)(ws + 115101696);        // [4096][1024] f32 (dead after scan_local)
  u16*   rtil   = (u16*)(ws + 131878912);          // [4096][1024] bf16
  float* SL     = (float*)(ws + 140267520);        // [1024][64][64] f32
  float* AC     = (float*)(ws + 157044736);        // [1024][64] f32
  u16*   ysB    = (u16*)(ws + 157306880);          // [4096][1024] bf16 combined intra-chunk y
  u16*   oB     = (u16*)(ws + 174084096);          // [4096][1024] bf16
  float* ysC    = (float*)(ws + 115101696);        // overlay: wbuf (f32 correction)

  convW<<<5120, 256, 0, stream>>>(rW, kW, vW, gW, oW, W_all);
  convLora<<<645, 256, 0, stream>>>(r_la, k_la, v_la, g_la, d_la,
                                    r_lb, k_lb, v_lb, g_lb, d_lb,
                                    r_ll, k_ll, v_ll, g_ll, d_ll,
                                    la_all, lb_all, ll_all);
  prep<<<4096, 256, 0, stream>>>(x, xw, lerpx, xB, dxB);

  // LoRA stage 1 (all 5): t1 = tanh(lerpx @ la^T)      [4096 x 64]
  gemm2<64, 64, 1><<<dim3(64, 1, 5), 256, 0, stream>>>(
      lerpx, 0L, la_all, 65536L, (void*)t1_all, 262144L, nullptr, nullptr, nullptr, MT, 64, 1024);
  // LoRA stage 2 (all 5): z = bf16(x + dx*(ll + t1 @ lb^T))   [4096 x 1024]
  gemm2<128, 128, 2><<<dim3(32, 8, 5), 256, 0, stream>>>(
      t1_all, 262144L, lb_all, 65536L, (void*)z_all, 4194304L, ll_all, xB, dxB, MT, 1024, 64);
  // d-outer stage 1: t2 = tanh(z_d @ d_la^T)
  gemm2<64, 64, 1><<<dim3(64, 1, 1), 256, 0, stream>>>(
      z_all + 4L * 4194304, 0L, la_all + 4L * 65536, 0L, (void*)t1_all, 0L, nullptr, nullptr, nullptr, MT, 64, 1024);
  // d-outer stage 2: w = exp(-exp(d_ll + t2 @ d_lb^T))  (f32)
  gemm2<128, 128, 3><<<dim3(32, 8, 1), 256, 0, stream>>>(
      t1_all, 0L, lb_all + 4L * 65536, 0L, (void*)wbuf, 0L, ll_all + 4096, nullptr, nullptr, MT, 1024, 64);
  // projections r,k,v,g = z @ W^T (bf16 out)
  gemm2<128, 128, 4><<<dim3(32, 8, 4), 256, 0, stream>>>(
      z_all, 4194304L, W_all, 1048576L, (void*)rkvg, 4194304L, nullptr, nullptr, nullptr, MT, 1024, 1024);

  // chunked WKV scan
  scan_local<<<1024, 512, 0, stream>>>(rkvg, rkvg + 4194304L, rkvg + 2L * 4194304, wbuf,
                                       uP, ysB, rtil, SL, AC);
  scan_prop<<<256, 256, 0, stream>>>(SL, AC, initS, out + 4194304);
  scan_corr<<<1024, 256, 0, stream>>>(SL, rtil, ysC);

  // o = silu(g) * groupnorm(y); out = o @ oW^T
  ln_silu<<<16384, 256, 0, stream>>>(ysB, ysC, rkvg + 3L * 4194304, lnw, lnb, oB);
  gemm2<128, 128, 0><<<dim3(32, 8, 1), 256, 0, stream>>>(
      oB, 0L, W_all + 4L * 1048576, 0L, (void*)out, 0L, nullptr, nullptr, nullptr, MT, 1024, 1024);
}

// Round 10
// 349.248 us; speedup vs baseline: 1.4700x; 1.0165x over previous
//
#include <hip/hip_runtime.h>
#include <hip/hip_bf16.h>

typedef unsigned short u16;
typedef unsigned int u32;
typedef __attribute__((ext_vector_type(2))) float f32x2;
typedef __attribute__((ext_vector_type(4))) float f32x4;
typedef __attribute__((ext_vector_type(8))) short s16x8;

#define AS1 __attribute__((address_space(1)))
#define AS3 __attribute__((address_space(3)))

#define NB 4
#define TTOK 1024
#define DD 1024
#define NH 16
#define HD 64
#define MT 4096      // B*T tokens
#define NCH 16       // chunks per (b,h)
#define CLEN 64      // chunk length

static __device__ __forceinline__ float b2f(u16 u) {
  union { unsigned int u; float f; } c; c.u = ((unsigned int)u) << 16; return c.f;
}
static __device__ __forceinline__ u16 f2b(float f) {
  union { float f; unsigned int u; } c; c.f = f;
  return (u16)((c.u + 0x7fffu + ((c.u >> 16) & 1u)) >> 16);
}
// direct global->LDS async copy, 16B per lane
static __device__ __forceinline__ void gload16(const u16* g, u16* l) {
  __builtin_amdgcn_global_load_lds((const AS1 u32*)g, (AS3 u32*)l, 16, 0, 0);
}
// LDS byte-offset swizzle (involution, keeps 16B chunks intact)
static __device__ __forceinline__ int swz(int lin) {
  return lin ^ (((lin >> 9) & 3) << 5) ^ (((lin >> 7) & 1) << 4);
}

// ---------------- weight conversion / packing ----------------
__global__ __launch_bounds__(256) void convW(const float* __restrict__ s0, const float* __restrict__ s1,
                                             const float* __restrict__ s2, const float* __restrict__ s3,
                                             const float* __restrict__ s4, u16* __restrict__ dst) {
  long f = ((long)blockIdx.x * 256 + threadIdx.x) << 2;   // 5 * 1048576 elems
  int sel = (int)(f >> 20);
  const float* s = sel == 0 ? s0 : sel == 1 ? s1 : sel == 2 ? s2 : sel == 3 ? s3 : s4;
  long off = f & 1048575;
  f32x4 v = *(const f32x4*)&s[off];
  ushort4 o; o.x = f2b(v[0]); o.y = f2b(v[1]); o.z = f2b(v[2]); o.w = f2b(v[3]);
  *(ushort4*)&dst[f] = o;
}

__global__ __launch_bounds__(256) void convLora(
    const float* a0, const float* a1, const float* a2, const float* a3, const float* a4,
    const float* b0, const float* b1, const float* b2, const float* b3, const float* b4,
    const float* l0, const float* l1, const float* l2, const float* l3, const float* l4,
    u16* __restrict__ laD, u16* __restrict__ lbD, float* __restrict__ llD) {
  long f = ((long)blockIdx.x * 256 + threadIdx.x) << 2;
  if (f < 327680) {            // 5 x 65536 la
    int sel = (int)(f >> 16); long off = f & 65535;
    const float* s = sel == 0 ? a0 : sel == 1 ? a1 : sel == 2 ? a2 : sel == 3 ? a3 : a4;
    f32x4 v = *(const f32x4*)&s[off];
    ushort4 o; o.x = f2b(v[0]); o.y = f2b(v[1]); o.z = f2b(v[2]); o.w = f2b(v[3]);
    *(ushort4*)&laD[f] = o;
  } else if (f < 655360) {     // 5 x 65536 lb
    long g = f - 327680;
    int sel = (int)(g >> 16); long off = g & 65535;
    const float* s = sel == 0 ? b0 : sel == 1 ? b1 : sel == 2 ? b2 : sel == 3 ? b3 : b4;
    f32x4 v = *(const f32x4*)&s[off];
    ushort4 o; o.x = f2b(v[0]); o.y = f2b(v[1]); o.z = f2b(v[2]); o.w = f2b(v[3]);
    *(ushort4*)&lbD[g] = o;
  } else if (f < 660480) {     // 5 x 1024 ll (f32 copy)
    long g = f - 655360;
    int sel = (int)(g >> 10); long off = g & 1023;
    const float* s = sel == 0 ? l0 : sel == 1 ? l1 : sel == 2 ? l2 : sel == 3 ? l3 : l4;
    *(f32x4*)&llD[g] = *(const f32x4*)&s[off];
  }
}

// ---------------- token shift prep: lerpx, xB, dxB (all bf16) ----------------
__global__ __launch_bounds__(256) void prep(const float* __restrict__ x, const float* __restrict__ xw,
                                            u16* __restrict__ lerpx, u16* __restrict__ xB,
                                            u16* __restrict__ dxB) {
  long f = ((long)blockIdx.x * 256 + threadIdx.x) << 2;
  int d = (int)(f & (DD - 1));
  int m = (int)(f >> 10);
  int t = m & (TTOK - 1);
  f32x4 xv = *(const f32x4*)&x[f];
  f32x4 xm = {};
  if (t > 0) xm = *(const f32x4*)&x[f - DD];
  f32x4 xwv = *(const f32x4*)&xw[d];
  f32x4 dx = xm - xv;
  f32x4 lp = xv + dx * xwv;
  ushort4 o; o.x = f2b(lp[0]); o.y = f2b(lp[1]); o.z = f2b(lp[2]); o.w = f2b(lp[3]);
  *(ushort4*)&lerpx[f] = o;
  ushort4 ox; ox.x = f2b(xv[0]); ox.y = f2b(xv[1]); ox.z = f2b(xv[2]); ox.w = f2b(xv[3]);
  *(ushort4*)&xB[f] = ox;
  ushort4 od; od.x = f2b(dx[0]); od.y = f2b(dx[1]); od.z = f2b(dx[2]); od.w = f2b(dx[3]);
  *(ushort4*)&dxB[f] = od;
}

// ---------------- bf16 MFMA GEMM, m97-style: BK=64, global_load_lds, swizzled LDS ----
// C[m][n] = sum_k A[m][k]*B[n][k].   blockIdx.x -> M tile (A-panel sharers co-XCD).
// EPI: 0 = store f32; 1 = store bf16(tanh); 2 = z-epilogue bf16(x + dx*(ll+acc));
//      3 = store f32 exp(-exp(ll+acc)); 4 = store bf16
template<int BM, int BN, int EPI>
__launch_bounds__(256)
__global__ void gemm2(const u16* __restrict__ Ab, long sAz,
                      const u16* __restrict__ Bb, long sBz,
                      void* __restrict__ Ob, long sOz,
                      const float* __restrict__ llb,
                      const u16* __restrict__ xB,
                      const u16* __restrict__ dxB,
                      int M, int N, int K) {
  __shared__ __align__(16) u16 As[BM * 64];
  __shared__ __align__(16) u16 Bs[BN * 64];
  const int z = blockIdx.z;
  const u16* A = Ab + (long)z * sAz;
  const u16* Bw = Bb + (long)z * sBz;
  const int m0 = blockIdx.x * BM;
  const int n0 = blockIdx.y * BN;
  const int tid = threadIdx.x;
  const int l = tid & 63;
  const int wv = tid >> 6;
  constexpr int WM = BM / 2, WN = BN / 2;
  constexpr int FM = WM / 16, FN = WN / 16;
  const int wm0 = (wv >> 1) * WM, wn0 = (wv & 1) * WN;
  const int lrow = l & 15, lk = (l >> 4) * 8;
  constexpr int GA = BM / 32, GB = BN / 32;   // 16B gloads per thread per tile
  int gA[GA], gB[GB];
#pragma unroll
  for (int q = 0; q < GA; ++q) {
    int d = (q * 256 + tid) * 16;
    int bb = swz(d);
    gA[q] = (m0 + (bb >> 7)) * K + ((bb & 127) >> 1);
  }
#pragma unroll
  for (int q = 0; q < GB; ++q) {
    int d = (q * 256 + tid) * 16;
    int bb = swz(d);
    gB[q] = (n0 + (bb >> 7)) * K + ((bb & 127) >> 1);
  }
  int aOff[FM][2], bOff[FN][2];
#pragma unroll
  for (int m = 0; m < FM; ++m)
#pragma unroll
    for (int kk = 0; kk < 2; ++kk)
      aOff[m][kk] = swz(((wm0 + m * 16 + lrow) << 7) + (kk << 6) + (lk << 1));
#pragma unroll
  for (int n = 0; n < FN; ++n)
#pragma unroll
    for (int kk = 0; kk < 2; ++kk)
      bOff[n][kk] = swz(((wn0 + n * 16 + lrow) << 7) + (kk << 6) + (lk << 1));
  f32x4 acc[FM][FN] = {};
  for (int k0 = 0; k0 < K; k0 += 64) {
    __syncthreads();
#pragma unroll
    for (int q = 0; q < GA; ++q)
      gload16(&A[(long)gA[q] + k0], (u16*)((char*)As + (q * 256 + tid) * 16));
#pragma unroll
    for (int q = 0; q < GB; ++q)
      gload16(&Bw[(long)gB[q] + k0], (u16*)((char*)Bs + (q * 256 + tid) * 16));
    __syncthreads();   // drains vmcnt -> LDS tile complete
#pragma unroll
    for (int kk = 0; kk < 2; ++kk) {
      s16x8 af[FM], bfr[FN];
#pragma unroll
      for (int m = 0; m < FM; ++m) af[m] = *(const s16x8*)((const char*)As + aOff[m][kk]);
#pragma unroll
      for (int n = 0; n < FN; ++n) bfr[n] = *(const s16x8*)((const char*)Bs + bOff[n][kk]);
#pragma unroll
      for (int m = 0; m < FM; ++m)
#pragma unroll
        for (int n = 0; n < FN; ++n)
          acc[m][n] = __builtin_amdgcn_mfma_f32_16x16x32_bf16(af[m], bfr[n], acc[m][n], 0, 0, 0);
    }
  }
#pragma unroll
  for (int m = 0; m < FM; ++m) {
#pragma unroll
    for (int n = 0; n < FN; ++n) {
      const int j = n0 + wn0 + n * 16 + lrow;
#pragma unroll
      for (int q = 0; q < 4; ++q) {
        const int i = m0 + wm0 + m * 16 + (l >> 4) * 4 + q;
        const long off = (long)i * N + j;
        float v = acc[m][n][q];
        if constexpr (EPI == 0) {
          ((float*)Ob + (long)z * sOz)[off] = v;
        } else if constexpr (EPI == 1) {
          ((u16*)Ob + (long)z * sOz)[off] = f2b(tanhf(v));
        } else if constexpr (EPI == 2) {
          float val = b2f(xB[off]) + b2f(dxB[off]) * (llb[(long)z * N + j] + v);
          ((u16*)Ob + (long)z * sOz)[off] = f2b(val);
        } else if constexpr (EPI == 3) {
          ((float*)Ob + (long)z * sOz)[off] = expf(-expf(llb[j] + v));
        } else {
          ((u16*)Ob + (long)z * sOz)[off] = f2b(v);
        }
      }
    }
  }
}

// ---------------- S1: chunk-local WKV scan, balanced waves + parallel rtil prefix ---
// Wave w owns state rows [8w,8w+8) for ALL j (lane = j); broadcast ds_read_b128 for
// r/k/w. rtil/A-product hoisted OUT of the main loop: a 3-step parallel prefix phase
// (segment products -> per-wave exclusive prefix -> parallel rtil) removes all
// wave-special serial work. Y8 strip combine every 8 steps as before.
__global__ __launch_bounds__(512) void scan_local(
    const u16* __restrict__ rP, const u16* __restrict__ kP,
    const u16* __restrict__ vP, const float* __restrict__ wP,
    const float* __restrict__ uP, u16* __restrict__ ysB,
    u16* __restrict__ rtil, float* __restrict__ SL, float* __restrict__ AC) {
  __shared__ __align__(16) float Rf[64 * 64];   // 16KB
  __shared__ __align__(16) float Kf[64 * 64];   // 16KB
  __shared__ __align__(16) float Wf[64 * 64];   // 16KB
  __shared__ __align__(16) u16 Vs[64 * 64];     // 8KB
  __shared__ __align__(16) char Ubuf[16384];    // union: {Rt u16[4096] + seg f32[512]} then Y8 f32[8][8][64]
  u16* Rt = (u16*)Ubuf;                         // [64][64] bf16 rtil tile (pre-phase)
  float* seg = (float*)(Ubuf + 12288);          // [8][64] segment products (pre-phase)
  float* Y8 = (float*)Ubuf;                     // [8][8][64] strips (main loop)
  const int bhc = blockIdx.x;
  const int c = bhc & (NCH - 1), h = (bhc >> 4) & (NH - 1), b = bhc >> 8;
  const int tid = threadIdx.x;
  const int l = tid & 63;                  // j column
  const int wv = tid >> 6;                 // wave id 0..7 -> state rows [8wv,8wv+8)
  const long base0 = ((long)(b * TTOK + c * CLEN) << 10) + h * HD;
  const int st = tid >> 3, sjo = (tid & 7) * 8;   // staging coords: 8 elems/thread
  // ---- stage v (bf16) and w (f32) via global_load_lds ----
  gload16(&vP[base0 + (long)st * DD + sjo], (u16*)Vs + tid * 8);
#pragma unroll
  for (int q = 0; q < 2; ++q) {
    int cidx = q * 512 + tid;
    int t = cidx >> 4, off = (cidx & 15) * 4;
    __builtin_amdgcn_global_load_lds((const AS1 u32*)&wP[base0 + (long)t * DD + off],
                                     (AS3 u32*)((float*)Wf + cidx * 4), 16, 0, 0);
  }
  // ---- reg-stage r,k: load bf16x8, convert once, write f32 LDS ----
  {
    s16x8 rv = *(const s16x8*)&rP[base0 + (long)st * DD + sjo];
    s16x8 kv = *(const s16x8*)&kP[base0 + (long)st * DD + sjo];
    f32x4 r0, r1, k0, k1;
#pragma unroll
    for (int e = 0; e < 4; ++e) {
      r0[e] = b2f((u16)rv[e]); r1[e] = b2f((u16)rv[e + 4]);
      k0[e] = b2f((u16)kv[e]); k1[e] = b2f((u16)kv[e + 4]);
    }
    *(f32x4*)&Rf[st * 64 + sjo] = r0; *(f32x4*)&Rf[st * 64 + sjo + 4] = r1;
    *(f32x4*)&Kf[st * 64 + sjo] = k0; *(f32x4*)&Kf[st * 64 + sjo + 4] = k1;
  }
  __syncthreads();                          // all staging complete
  // ---- P1: per-wave segment decay products (channel j = l, t in [8wv,8wv+8)) ----
  {
    float p = 1.f;
#pragma unroll
    for (int q = 0; q < 8; ++q) p *= Wf[(8 * wv + q) * 64 + l];
    seg[wv * 64 + l] = p;
  }
  __syncthreads();
  // ---- P2: exclusive prefix per wave; rtil tile in parallel; AC ----
  {
    float sv[8];
#pragma unroll
    for (int w2 = 0; w2 < 8; ++w2) sv[w2] = seg[w2 * 64 + l];
    float pre = 1.f;
    for (int w2 = 0; w2 < wv; ++w2) pre *= sv[w2];   // wave-uniform trip count
    float a = pre;
#pragma unroll
    for (int q = 0; q < 8; ++q) {
      const int tt = 8 * wv + q;
      Rt[tt * 64 + l] = f2b(Rf[tt * 64 + l] * a);    // r_t * A_{t-1}
      a *= Wf[tt * 64 + l];
    }
    if (wv == 0) {
      float all = sv[0];
#pragma unroll
      for (int w2 = 1; w2 < 8; ++w2) all *= sv[w2];
      AC[(long)bhc * 64 + l] = all;
    }
  }
  __syncthreads();
  // ---- P3: bulk rtil store (coalesced s16x8) ----
  *(s16x8*)&rtil[base0 + (long)st * DD + sjo] = *(const s16x8*)&Rt[st * 64 + sjo];
  __syncthreads();                          // Rt region free -> Y8 reuse safe
  // ---- main loop: balanced, no wave-special work ----
  f32x2 u2[4];
#pragma unroll
  for (int e = 0; e < 4; ++e) u2[e] = *(const f32x2*)&uP[h * HD + 8 * wv + 2 * e];
  f32x2 s2[4] = {};
  for (int t0 = 0; t0 < CLEN; t0 += 8) {
    float y8[8];
#pragma unroll
    for (int q = 0; q < 8; ++q) {
      const int tt = t0 + q;
      const int ro = tt * 64 + 8 * wv;
      const f32x4 rA = *(const f32x4*)&Rf[ro];      // wave-uniform -> broadcast
      const f32x4 rB = *(const f32x4*)&Rf[ro + 4];
      const f32x4 kA = *(const f32x4*)&Kf[ro];
      const f32x4 kB = *(const f32x4*)&Kf[ro + 4];
      const f32x4 wA = *(const f32x4*)&Wf[ro];
      const f32x4 wB = *(const f32x4*)&Wf[ro + 4];
      const float vj = b2f(Vs[tt * 64 + l]);
      const f32x2 vj2 = {vj, vj};
      f32x2 y2 = {0.f, 0.f};
      {
        const f32x2 rp = {rA[0], rA[1]}, kp = {kA[0], kA[1]}, wp = {wA[0], wA[1]};
        const f32x2 kv = kp * vj2;
        y2 = __builtin_elementwise_fma(rp, __builtin_elementwise_fma(u2[0], kv, s2[0]), y2);
        s2[0] = __builtin_elementwise_fma(wp, s2[0], kv);
      }
      {
        const f32x2 rp = {rA[2], rA[3]}, kp = {kA[2], kA[3]}, wp = {wA[2], wA[3]};
        const f32x2 kv = kp * vj2;
        y2 = __builtin_elementwise_fma(rp, __builtin_elementwise_fma(u2[1], kv, s2[1]), y2);
        s2[1] = __builtin_elementwise_fma(wp, s2[1], kv);
      }
      {
        const f32x2 rp = {rB[0], rB[1]}, kp = {kB[0], kB[1]}, wp = {wB[0], wB[1]};
        const f32x2 kv = kp * vj2;
        y2 = __builtin_elementwise_fma(rp, __builtin_elementwise_fma(u2[2], kv, s2[2]), y2);
        s2[2] = __builtin_elementwise_fma(wp, s2[2], kv);
      }
      {
        const f32x2 rp = {rB[2], rB[3]}, kp = {kB[2], kB[3]}, wp = {wB[2], wB[3]};
        const f32x2 kv = kp * vj2;
        y2 = __builtin_elementwise_fma(rp, __builtin_elementwise_fma(u2[3], kv, s2[3]), y2);
        s2[3] = __builtin_elementwise_fma(wp, s2[3], kv);
      }
      y8[q] = y2[0] + y2[1];
    }
    // dump wave strip, combine across the 8 waves, store bf16
#pragma unroll
    for (int q = 0; q < 8; ++q) Y8[(wv * 8 + q) * 64 + l] = y8[q];
    __syncthreads();
    {
      float acc = Y8[wv * 64 + l];         // thread -> (t' = wv, j = l); Y8[0][wv][l]
#pragma unroll
      for (int w2 = 1; w2 < 8; ++w2) acc += Y8[(w2 * 8 + wv) * 64 + l];
      ysB[base0 + (long)(t0 + wv) * DD + l] = f2b(acc);
    }
    __syncthreads();
  }
  // state out
#pragma unroll
  for (int e = 0; e < 4; ++e) {
    SL[((long)bhc * 64 + 8 * wv + 2 * e) * 64 + l] = s2[e][0];
    SL[((long)bhc * 64 + 8 * wv + 2 * e + 1) * 64 + l] = s2[e][1];
  }
}

// ---------------- S2a: propagate chunk-boundary states; overwrite SL[c] with S_in(c) ----------------
__global__ __launch_bounds__(256) void scan_prop(
    float* __restrict__ SL, const float* __restrict__ AC,
    const float* __restrict__ initS, float* __restrict__ st1) {
  const int bh = blockIdx.x >> 2;          // 64 bh
  const int jq = blockIdx.x & 3;
  const int h = bh & (NH - 1);
  const int i = threadIdx.x >> 2;
  const int jo = jq * 16 + (threadIdx.x & 3) * 4;
  f32x4 sin4 = *(const f32x4*)(initS + ((long)h * 64 + i) * 64 + jo);
  for (int cc = 0; cc < NCH; ++cc) {
    const long bhc = (long)bh * NCH + cc;
    f32x4* slp = (f32x4*)(SL + (bhc * 64 + i) * 64 + jo);
    const float Ai = AC[bhc * 64 + i];
    f32x4 sl = *slp;
    *slp = sin4;                           // S_in(c) for S2b
    sin4 = Ai * sin4 + sl;
  }
  *(f32x4*)(st1 + ((long)bh * 64 + i) * 64 + jo) = sin4;
}

// ---------------- S2b: cross-chunk correction ysC = rtil @ S_in (store, f32) -------
__global__ __launch_bounds__(256) void scan_corr(
    const float* __restrict__ SL, const u16* __restrict__ rtil, float* __restrict__ ysC) {
  __shared__ __align__(16) float S[64 * 64];
  const int bhc = blockIdx.x;
  const int c = bhc & (NCH - 1), h = (bhc >> 4) & (NH - 1), b = bhc >> 8;
  const int tid = threadIdx.x;
  const f32x4* sp = (const f32x4*)(SL + (long)bhc * 4096);
  for (int q = tid; q < 1024; q += 256) ((f32x4*)S)[q] = sp[q];
  __syncthreads();
  const int t = tid >> 2, jg = (tid & 3) * 16;
  const long base = ((long)(b * TTOK + c * CLEN + t) * DD) + h * HD;
  f32x4 yacc[4] = {};
  const u16* rp = rtil + base;
#pragma unroll 8
  for (int i = 0; i < 64; ++i) {
    const float r = b2f(rp[i]);
    const f32x4* srow = (const f32x4*)&S[i * 64 + jg];
#pragma unroll
    for (int e = 0; e < 4; ++e) yacc[e] += r * srow[e];
  }
  f32x4* yp = (f32x4*)(ysC + base + jg);
#pragma unroll
  for (int e = 0; e < 4; ++e) yp[e] = yacc[e];
}

// ---------------- GroupNorm(hd=64) * SiLU(g) -> o (bf16) ----------------
__global__ __launch_bounds__(256) void ln_silu(
    const u16* __restrict__ ysB, const float* __restrict__ ysC,
    const u16* __restrict__ gP,
    const float* __restrict__ lnw, const float* __restrict__ lnb,
    u16* __restrict__ oB) {
  const int ridx = blockIdx.x * 4 + (threadIdx.x >> 6);   // (token*16 + h)
  const int lane = threadIdx.x & 63;
  const long basem = (long)ridx * 64;
  const float y = b2f(ysB[basem + lane]) + ysC[basem + lane];
  float su = y, sq = y * y;
#pragma unroll
  for (int msk = 1; msk < 64; msk <<= 1) {
    su += __shfl_xor(su, msk, 64);
    sq += __shfl_xor(sq, msk, 64);
  }
  const float mean = su * (1.f / 64.f);
  const float var = sq * (1.f / 64.f) - mean * mean;
  const float rs = rsqrtf(var + 1e-5f);
  const float g = b2f(gP[basem + lane]);
  const float silu = g / (1.f + expf(-g));
  const float val = silu * ((y - mean) * rs * lnw[lane] + lnb[lane]);
  oB[basem + lane] = f2b(val);
}

// ---------------- launcher ----------------
extern "C" void kernel_launch(void* const* d_in, const int* in_sizes, int n_in,
                              void* d_out, int out_size, void* d_ws, size_t ws_size,
                              hipStream_t stream) {
  const float* x   = (const float*)d_in[0];
  const float* xw  = (const float*)d_in[1];
  const float* rW  = (const float*)d_in[2];
  const float* kW  = (const float*)d_in[3];
  const float* vW  = (const float*)d_in[4];
  const float* gW  = (const float*)d_in[5];
  const float* r_la = (const float*)d_in[6],  *r_lb = (const float*)d_in[7],  *r_ll = (const float*)d_in[8];
  const float* k_la = (const float*)d_in[9],  *k_lb = (const float*)d_in[10], *k_ll = (const float*)d_in[11];
  const float* v_la = (const float*)d_in[12], *v_lb = (const float*)d_in[13], *v_ll = (const float*)d_in[14];
  const float* g_la = (const float*)d_in[15], *g_lb = (const float*)d_in[16], *g_ll = (const float*)d_in[17];
  const float* d_la = (const float*)d_in[18], *d_lb = (const float*)d_in[19], *d_ll = (const float*)d_in[20];
  const float* lnw = (const float*)d_in[21];
  const float* lnb = (const float*)d_in[22];
  const float* oW  = (const float*)d_in[23];
  const float* initS = (const float*)d_in[24];
  const float* uP  = (const float*)d_in[25];
  float* out = (float*)d_out;

  // workspace layout (~183 MB)
  char* ws = (char*)d_ws;
  u16*   W_all  = (u16*)(ws + 0);                  // [5][1024][1024] bf16 (r,k,v,g,o)
  u16*   la_all = (u16*)(ws + 10485760);           // [5][64][1024]
  u16*   lb_all = (u16*)(ws + 11141120);           // [5][1024][64]
  float* ll_all = (float*)(ws + 11796480);         // [5][1024]
  u16*   lerpx  = (u16*)(ws + 11816960);           // [4096][1024] bf16 (dead after lora1)
  u16*   xB     = (u16*)(ws + 20205568);           // [4096][1024] bf16 (dead after z-stage2)
  u16*   dxB    = (u16*)(ws + 28594176);           // [4096][1024] bf16 (dead after z-stage2)
  u16*   t1_all = (u16*)(ws + 36982784);           // [5][4096][64] bf16
  u16*   z_all  = (u16*)(ws + 39604224);           // [5][4096][1024] bf16 (dead after projections)
  u16*   rkvg   = (u16*)(ws + 81547264);           // [4][4096][1024] bf16
  float* wbuf   = (float*)(ws + 115101696);        // [4096][1024] f32 (dead after scan_local)
  u16*   rtil   = (u16*)(ws + 131878912);          // [4096][1024] bf16
  float* SL     = (float*)(ws + 140267520);        // [1024][64][64] f32
  float* AC     = (float*)(ws + 157044736);        // [1024][64] f32
  u16*   ysB    = (u16*)(ws + 157306880);          // [4096][1024] bf16 combined intra-chunk y
  u16*   oB     = (u16*)(ws + 174084096);          // [4096][1024] bf16
  float* ysC    = (float*)(ws + 115101696);        // overlay: wbuf (f32 correction)

  convW<<<5120, 256, 0, stream>>>(rW, kW, vW, gW, oW, W_all);
  convLora<<<645, 256, 0, stream>>>(r_la, k_la, v_la, g_la, d_la,
                                    r_lb, k_lb, v_lb, g_lb, d_lb,
                                    r_ll, k_ll, v_ll, g_ll, d_ll,
                                    la_all, lb_all, ll_all);
  prep<<<4096, 256, 0, stream>>>(x, xw, lerpx, xB, dxB);

  // LoRA stage 1 (all 5): t1 = tanh(lerpx @ la^T)      [4096 x 64]
  gemm2<64, 64, 1><<<dim3(64, 1, 5), 256, 0, stream>>>(
      lerpx, 0L, la_all, 65536L, (void*)t1_all, 262144L, nullptr, nullptr, nullptr, MT, 64, 1024);
  // LoRA stage 2 (all 5): z = bf16(x + dx*(ll + t1 @ lb^T))   [4096 x 1024]
  gemm2<128, 128, 2><<<dim3(32, 8, 5), 256, 0, stream>>>(
      t1_all, 262144L, lb_all, 65536L, (void*)z_all, 4194304L, ll_all, xB, dxB, MT, 1024, 64);
  // d-outer stage 1: t2 = tanh(z_d @ d_la^T)
  gemm2<64, 64, 1><<<dim3(64, 1, 1), 256, 0, stream>>>(
      z_all + 4L * 4194304, 0L, la_all + 4L * 65536, 0L, (void*)t1_all, 0L, nullptr, nullptr, nullptr, MT, 64, 1024);
  // d-outer stage 2: w = exp(-exp(d_ll + t2 @ d_lb^T))  (f32)
  gemm2<128, 128, 3><<<dim3(32, 8, 1), 256, 0, stream>>>(
      t1_all, 0L, lb_all + 4L * 65536, 0L, (void*)wbuf, 0L, ll_all + 4096, nullptr, nullptr, MT, 1024, 64);
  // projections r,k,v,g = z @ W^T (bf16 out)
  gemm2<128, 128, 4><<<dim3(32, 8, 4), 256, 0, stream>>>(
      z_all, 4194304L, W_all, 1048576L, (void*)rkvg, 4194304L, nullptr, nullptr, nullptr, MT, 1024, 1024);

  // chunked WKV scan
  scan_local<<<1024, 512, 0, stream>>>(rkvg, rkvg + 4194304L, rkvg + 2L * 4194304, wbuf,
                                       uP, ysB, rtil, SL, AC);
  scan_prop<<<256, 256, 0, stream>>>(SL, AC, initS, out + 4194304);
  scan_corr<<<1024, 256, 0, stream>>>(SL, rtil, ysC);

  // o = silu(g) * groupnorm(y); out = o @ oW^T
  ln_silu<<<16384, 256, 0, stream>>>(ysB, ysC, rkvg + 3L * 4194304, lnw, lnb, oB);
  gemm2<128, 128, 0><<<dim3(32, 8, 1), 256, 0, stream>>>(
      oB, 0L, W_all + 4L * 1048576, 0L, (void*)out, 0L, nullptr, nullptr, nullptr, MT, 1024, 1024);
}